// Round 1
// baseline (469.987 us; speedup 1.0000x reference)
//
#include <hip/hip_runtime.h>
#include <hip/hip_bf16.h>

using short8 = __attribute__((ext_vector_type(8))) short;
using f32x4  = __attribute__((ext_vector_type(4))) float;

#define DEV __device__ __forceinline__

DEV unsigned short f2b(float f) {
  union { float f; unsigned u; } cv; cv.f = f;
  unsigned r = (cv.u + 0x7fffu + ((cv.u >> 16) & 1u)) >> 16;
  return (unsigned short)r;
}

// ---- transpose + convert: fp32 src[K][N] -> bf16 dst[N][K] ----
__global__ void k_tcvt(const float* __restrict__ src, unsigned short* __restrict__ dst,
                       int K, int N) {
  __shared__ float tile[32][33];
  int n0 = blockIdx.x * 32, k0 = blockIdx.y * 32;
  int tx = threadIdx.x, ty = threadIdx.y;
#pragma unroll
  for (int j = 0; j < 4; ++j)
    tile[ty + j * 8][tx] = src[(size_t)(k0 + ty + j * 8) * N + (n0 + tx)];
  __syncthreads();
#pragma unroll
  for (int j = 0; j < 4; ++j)
    dst[(size_t)(n0 + ty + j * 8) * K + (k0 + tx)] = f2b(tile[tx][ty + j * 8]);
}

// ---- bf16 transpose: src[BH][2048][64] -> dst[BH][64][2048] ----
__global__ void k_tv(const unsigned short* __restrict__ src, unsigned short* __restrict__ dst) {
  __shared__ unsigned short tile[32][33];
  int d0 = blockIdx.x * 32, s0 = blockIdx.y * 32;
  size_t base = (size_t)blockIdx.z * 2048 * 64;
  int tx = threadIdx.x, ty = threadIdx.y;
#pragma unroll
  for (int j = 0; j < 4; ++j)
    tile[ty + j * 8][tx] = src[base + (size_t)(s0 + ty + j * 8) * 64 + (d0 + tx)];
  __syncthreads();
#pragma unroll
  for (int j = 0; j < 4; ++j)
    dst[base + (size_t)(d0 + ty + j * 8) * 2048 + (s0 + tx)] = tile[tx][ty + j * 8];
}

// ---- LayerNorm: fp32 in [rows][1024] -> bf16 out ----
__global__ __launch_bounds__(256) void k_ln(const float* __restrict__ x,
                                            const float* __restrict__ g,
                                            const float* __restrict__ b,
                                            unsigned short* __restrict__ y) {
  int row = blockIdx.x, tid = threadIdx.x;
  float4 v = reinterpret_cast<const float4*>(x + (size_t)row * 1024)[tid];
  float s  = v.x + v.y + v.z + v.w;
  float s2 = v.x * v.x + v.y * v.y + v.z * v.z + v.w * v.w;
#pragma unroll
  for (int m = 1; m < 64; m <<= 1) { s += __shfl_xor(s, m); s2 += __shfl_xor(s2, m); }
  __shared__ float ps[8];
  int w = tid >> 6;
  if ((tid & 63) == 0) { ps[w] = s; ps[4 + w] = s2; }
  __syncthreads();
  s  = ps[0] + ps[1] + ps[2] + ps[3];
  s2 = ps[4] + ps[5] + ps[6] + ps[7];
  float mu   = s * (1.0f / 1024.0f);
  float var  = fmaxf(s2 * (1.0f / 1024.0f) - mu * mu, 0.f);
  float rstd = rsqrtf(var + 1e-5f);
  float4 gv = reinterpret_cast<const float4*>(g)[tid];
  float4 bv = reinterpret_cast<const float4*>(b)[tid];
  ushort4 o;
  o.x = f2b((v.x - mu) * rstd * gv.x + bv.x);
  o.y = f2b((v.y - mu) * rstd * gv.y + bv.y);
  o.z = f2b((v.z - mu) * rstd * gv.z + bv.z);
  o.w = f2b((v.w - mu) * rstd * gv.w + bv.w);
  reinterpret_cast<ushort4*>(y + (size_t)row * 1024)[tid] = o;
}

// ---- GEMM: C[M][N] = A[M][K] (bf16) * BT[N][K]^T (bf16) + bias, fused epilogue ----
enum { EPI_QKV = 0, EPI_RESID = 1, EPI_GELU = 2 };

template <int EPI>
__global__ __launch_bounds__(256) void k_gemm(
    const unsigned short* __restrict__ A, const unsigned short* __restrict__ BT,
    const float* __restrict__ bias, int M, int N, int K,
    float* __restrict__ outf, const float* __restrict__ resid,
    unsigned short* __restrict__ outb,
    unsigned short* __restrict__ qb, unsigned short* __restrict__ kb,
    unsigned short* __restrict__ vb) {
  __shared__ __align__(16) unsigned short As[128][32];
  __shared__ __align__(16) unsigned short Bs[128][32];
  int m0 = blockIdx.y * 128, n0 = blockIdx.x * 128;
  int tid = threadIdx.x;
  int lane = tid & 63, wid = tid >> 6;
  int wr = wid >> 1, wc = wid & 1;
  int l15 = lane & 15, g = lane >> 4;
  int srow = tid >> 1, scol = (tid & 1) * 16;
  f32x4 acc[4][4] = {};
  const short8* ap = reinterpret_cast<const short8*>(A + (size_t)(m0 + srow) * K + scol);
  const short8* bp = reinterpret_cast<const short8*>(BT + (size_t)(n0 + srow) * K + scol);
  short8 av0 = ap[0], av1 = ap[1];
  short8 bv0 = bp[0], bv1 = bp[1];
  for (int k0 = 0; k0 < K; k0 += 32) {
    __syncthreads();
    *reinterpret_cast<short8*>(&As[srow][scol])     = av0;
    *reinterpret_cast<short8*>(&As[srow][scol + 8]) = av1;
    *reinterpret_cast<short8*>(&Bs[srow][scol])     = bv0;
    *reinterpret_cast<short8*>(&Bs[srow][scol + 8]) = bv1;
    __syncthreads();
    if (k0 + 32 < K) {
      const short8* ap2 = reinterpret_cast<const short8*>(A + (size_t)(m0 + srow) * K + (k0 + 32) + scol);
      const short8* bp2 = reinterpret_cast<const short8*>(BT + (size_t)(n0 + srow) * K + (k0 + 32) + scol);
      av0 = ap2[0]; av1 = ap2[1]; bv0 = bp2[0]; bv1 = bp2[1];
    }
    short8 af[4], bfr[4];
#pragma unroll
    for (int i = 0; i < 4; ++i)
      af[i] = *reinterpret_cast<const short8*>(&As[wr * 64 + i * 16 + l15][g * 8]);
#pragma unroll
    for (int i = 0; i < 4; ++i)
      bfr[i] = *reinterpret_cast<const short8*>(&Bs[wc * 64 + i * 16 + l15][g * 8]);
#pragma unroll
    for (int mi = 0; mi < 4; ++mi)
#pragma unroll
      for (int ni = 0; ni < 4; ++ni)
        acc[mi][ni] = __builtin_amdgcn_mfma_f32_16x16x32_bf16(af[mi], bfr[ni], acc[mi][ni], 0, 0, 0);
  }
#pragma unroll
  for (int mi = 0; mi < 4; ++mi) {
#pragma unroll
    for (int ni = 0; ni < 4; ++ni) {
      int row0 = m0 + wr * 64 + mi * 16 + g * 4;
      int col  = n0 + wc * 64 + ni * 16 + l15;
      float bcol = bias[col];
#pragma unroll
      for (int j = 0; j < 4; ++j) {
        int r = row0 + j;
        float vv = acc[mi][ni][j] + bcol;
        if (EPI == EPI_QKV) {
          int which = col >> 10;
          int hc = col & 1023;
          int h = hc >> 6, d = hc & 63;
          int bb = r >> 11, ss = r & 2047;
          size_t idx = (((size_t)(bb * 16 + h)) * 2048 + ss) * 64 + d;
          unsigned short bv_ = f2b(vv);
          if (which == 0)      qb[idx] = bv_;
          else if (which == 1) kb[idx] = bv_;
          else                 vb[idx] = bv_;
        } else if (EPI == EPI_RESID) {
          size_t idx = (size_t)r * N + col;
          outf[idx] = vv + resid[idx];
        } else {
          float ge = 0.5f * vv * (1.0f + erff(vv * 0.70710678118654752f));
          outb[(size_t)r * N + col] = f2b(ge);
        }
      }
    }
  }
}

// ---- flash attention: grid (qblk=32, bh=32), 4 waves x 16 q-rows ----
__global__ __launch_bounds__(256) void k_attn(
    const unsigned short* __restrict__ qb, const unsigned short* __restrict__ kb,
    const unsigned short* __restrict__ vt, unsigned short* __restrict__ attn_out) {
  __shared__ __align__(16) unsigned short Plds[4][16][32];
  int qblk = blockIdx.x, bh = blockIdx.y;
  int b = bh >> 4, h = bh & 15;
  int tid = threadIdx.x;
  int lane = tid & 63, wid = tid >> 6;
  int l15 = lane & 15, g = lane >> 4;
  int q0 = qblk * 64 + wid * 16;
  const unsigned short* Qb = qb + (size_t)bh * 2048 * 64;
  const unsigned short* Kb = kb + (size_t)bh * 2048 * 64;
  const unsigned short* Vt = vt + (size_t)bh * 64 * 2048;
  short8 qf0 = *reinterpret_cast<const short8*>(&Qb[(size_t)(q0 + l15) * 64 + g * 8]);
  short8 qf1 = *reinterpret_cast<const short8*>(&Qb[(size_t)(q0 + l15) * 64 + 32 + g * 8]);
  float mj[4], lj[4];
  f32x4 o[4] = {};
#pragma unroll
  for (int j = 0; j < 4; ++j) { mj[j] = -1e30f; lj[j] = 0.f; }
  for (int t0 = 0; t0 < 2048; t0 += 32) {
    f32x4 sc[2] = {};
#pragma unroll
    for (int c = 0; c < 2; ++c) {
      short8 kf0 = *reinterpret_cast<const short8*>(&Kb[(size_t)(t0 + c * 16 + l15) * 64 + g * 8]);
      short8 kf1 = *reinterpret_cast<const short8*>(&Kb[(size_t)(t0 + c * 16 + l15) * 64 + 32 + g * 8]);
      sc[c] = __builtin_amdgcn_mfma_f32_16x16x32_bf16(qf0, kf0, sc[c], 0, 0, 0);
      sc[c] = __builtin_amdgcn_mfma_f32_16x16x32_bf16(qf1, kf1, sc[c], 0, 0, 0);
    }
#pragma unroll
    for (int j = 0; j < 4; ++j) {
      float s0 = sc[0][j] * 0.125f;
      float s1 = sc[1][j] * 0.125f;
      float mx = fmaxf(s0, s1);
#pragma unroll
      for (int mk = 1; mk < 16; mk <<= 1) mx = fmaxf(mx, __shfl_xor(mx, mk));
      float mnew = fmaxf(mj[j], mx);
      float efac = __expf(mj[j] - mnew);
      float p0 = __expf(s0 - mnew);
      float p1 = __expf(s1 - mnew);
      float ts = p0 + p1;
#pragma unroll
      for (int mk = 1; mk < 16; mk <<= 1) ts += __shfl_xor(ts, mk);
      lj[j] = lj[j] * efac + ts;
      mj[j] = mnew;
#pragma unroll
      for (int ct = 0; ct < 4; ++ct) o[ct][j] *= efac;
      Plds[wid][g * 4 + j][l15]      = f2b(p0);
      Plds[wid][g * 4 + j][16 + l15] = f2b(p1);
    }
    short8 pf = *reinterpret_cast<const short8*>(&Plds[wid][l15][g * 8]);
#pragma unroll
    for (int ct = 0; ct < 4; ++ct) {
      short8 vf = *reinterpret_cast<const short8*>(&Vt[(size_t)(ct * 16 + l15) * 2048 + t0 + g * 8]);
      o[ct] = __builtin_amdgcn_mfma_f32_16x16x32_bf16(pf, vf, o[ct], 0, 0, 0);
    }
  }
#pragma unroll
  for (int j = 0; j < 4; ++j) {
    float inv = 1.0f / lj[j];
    int s = q0 + g * 4 + j;
    size_t t = (size_t)b * 2048 + s;
#pragma unroll
    for (int ct = 0; ct < 4; ++ct)
      attn_out[t * 1024 + h * 64 + ct * 16 + l15] = f2b(o[ct][j] * inv);
  }
}

extern "C" void kernel_launch(void* const* d_in, const int* in_sizes, int n_in,
                              void* d_out, int out_size, void* d_ws, size_t ws_size,
                              hipStream_t stream) {
  (void)in_sizes; (void)n_in; (void)out_size; (void)ws_size;
  const float* x      = (const float*)d_in[0];
  const float* ln1_g  = (const float*)d_in[1];
  const float* ln1_b  = (const float*)d_in[2];
  const float* w_qkv  = (const float*)d_in[3];
  const float* b_qkv  = (const float*)d_in[4];
  const float* w_ao   = (const float*)d_in[5];
  const float* b_ao   = (const float*)d_in[6];
  const float* ln2_g  = (const float*)d_in[7];
  const float* ln2_b  = (const float*)d_in[8];
  const float* w_fc   = (const float*)d_in[9];
  const float* b_fc   = (const float*)d_in[10];
  const float* w_proj = (const float*)d_in[11];
  const float* b_proj = (const float*)d_in[12];
  float* out = (float*)d_out;

  char* ws = (char*)d_ws;
  size_t o = 0;
  auto nxt = [&](size_t bytes) { void* p = ws + o; o += (bytes + 255) & ~(size_t)255; return p; };
  unsigned short* wT_qkv  = (unsigned short*)nxt((size_t)3072 * 1024 * 2);
  unsigned short* wT_ao   = (unsigned short*)nxt((size_t)1024 * 1024 * 2);
  unsigned short* wT_fc   = (unsigned short*)nxt((size_t)4096 * 1024 * 2);
  unsigned short* wT_proj = (unsigned short*)nxt((size_t)1024 * 4096 * 2);
  unsigned short* h_ln    = (unsigned short*)nxt((size_t)4096 * 1024 * 2);
  unsigned short* qbuf    = (unsigned short*)nxt((size_t)4096 * 1024 * 2);
  unsigned short* kbuf    = (unsigned short*)nxt((size_t)4096 * 1024 * 2);
  unsigned short* vbuf    = (unsigned short*)nxt((size_t)4096 * 1024 * 2);
  unsigned short* vtb     = (unsigned short*)nxt((size_t)4096 * 1024 * 2);
  float*          out1    = (float*)nxt((size_t)4096 * 1024 * 4);
  unsigned short* fc_buf  = qbuf;  // reuse qkv region (33.5 MB) after attention
  unsigned short* attn_o  = vbuf;  // reuse vbuf after V-transpose

  dim3 b32(32, 8, 1);
  k_tcvt<<<dim3(96, 32), b32, 0, stream>>>(w_qkv, wT_qkv, 1024, 3072);
  k_tcvt<<<dim3(32, 32), b32, 0, stream>>>(w_ao, wT_ao, 1024, 1024);
  k_tcvt<<<dim3(128, 32), b32, 0, stream>>>(w_fc, wT_fc, 1024, 4096);
  k_tcvt<<<dim3(32, 128), b32, 0, stream>>>(w_proj, wT_proj, 4096, 1024);

  k_ln<<<4096, 256, 0, stream>>>(x, ln1_g, ln1_b, h_ln);
  k_gemm<EPI_QKV><<<dim3(24, 32), 256, 0, stream>>>(h_ln, wT_qkv, b_qkv, 4096, 3072, 1024,
                                                    nullptr, nullptr, nullptr, qbuf, kbuf, vbuf);
  k_tv<<<dim3(2, 64, 32), b32, 0, stream>>>(vbuf, vtb);
  k_attn<<<dim3(32, 32), 256, 0, stream>>>(qbuf, kbuf, vtb, attn_o);
  k_gemm<EPI_RESID><<<dim3(8, 32), 256, 0, stream>>>(attn_o, wT_ao, b_ao, 4096, 1024, 1024,
                                                     out1, x, nullptr, nullptr, nullptr, nullptr);
  k_ln<<<4096, 256, 0, stream>>>(out1, ln2_g, ln2_b, h_ln);
  k_gemm<EPI_GELU><<<dim3(32, 32), 256, 0, stream>>>(h_ln, wT_fc, b_fc, 4096, 4096, 1024,
                                                     nullptr, nullptr, fc_buf, nullptr, nullptr, nullptr);
  k_gemm<EPI_RESID><<<dim3(8, 32), 256, 0, stream>>>(fc_buf, wT_proj, b_proj, 4096, 1024, 4096,
                                                     out, out1, nullptr, nullptr, nullptr, nullptr);
}

// Round 2
// 387.093 us; speedup vs baseline: 1.2141x; 1.2141x over previous
//
#include <hip/hip_runtime.h>
#include <hip/hip_bf16.h>

using short8 = __attribute__((ext_vector_type(8))) short;
using f32x4  = __attribute__((ext_vector_type(4))) float;

#define DEV __device__ __forceinline__

DEV unsigned short f2b(float f) {
  union { float f; unsigned u; } cv; cv.f = f;
  unsigned r = (cv.u + 0x7fffu + ((cv.u >> 16) & 1u)) >> 16;
  return (unsigned short)r;
}

typedef const __attribute__((address_space(1))) unsigned int* gp1;
typedef __attribute__((address_space(3))) unsigned int* lp3;
DEV void gl16(const void* g, void* l) {
  __builtin_amdgcn_global_load_lds((gp1)g, (lp3)l, 16, 0, 0);
}

// ---- transpose + convert: fp32 src[K][N] -> bf16 dst[N][K] ----
__global__ void k_tcvt(const float* __restrict__ src, unsigned short* __restrict__ dst,
                       int K, int N) {
  __shared__ float tile[32][33];
  int n0 = blockIdx.x * 32, k0 = blockIdx.y * 32;
  int tx = threadIdx.x, ty = threadIdx.y;
#pragma unroll
  for (int j = 0; j < 4; ++j)
    tile[ty + j * 8][tx] = src[(size_t)(k0 + ty + j * 8) * N + (n0 + tx)];
  __syncthreads();
#pragma unroll
  for (int j = 0; j < 4; ++j)
    dst[(size_t)(n0 + ty + j * 8) * K + (k0 + tx)] = f2b(tile[tx][ty + j * 8]);
}

// ---- bf16 transpose: src[BH][2048][64] -> dst[BH][64][2048] ----
__global__ void k_tv(const unsigned short* __restrict__ src, unsigned short* __restrict__ dst) {
  __shared__ unsigned short tile[32][33];
  int d0 = blockIdx.x * 32, s0 = blockIdx.y * 32;
  size_t base = (size_t)blockIdx.z * 2048 * 64;
  int tx = threadIdx.x, ty = threadIdx.y;
#pragma unroll
  for (int j = 0; j < 4; ++j)
    tile[ty + j * 8][tx] = src[base + (size_t)(s0 + ty + j * 8) * 64 + (d0 + tx)];
  __syncthreads();
#pragma unroll
  for (int j = 0; j < 4; ++j)
    dst[base + (size_t)(d0 + ty + j * 8) * 2048 + (s0 + tx)] = tile[tx][ty + j * 8];
}

// ---- LayerNorm: fp32 in [rows][1024] -> bf16 out ----
__global__ __launch_bounds__(256) void k_ln(const float* __restrict__ x,
                                            const float* __restrict__ g,
                                            const float* __restrict__ b,
                                            unsigned short* __restrict__ y) {
  int row = blockIdx.x, tid = threadIdx.x;
  float4 v = reinterpret_cast<const float4*>(x + (size_t)row * 1024)[tid];
  float s  = v.x + v.y + v.z + v.w;
  float s2 = v.x * v.x + v.y * v.y + v.z * v.z + v.w * v.w;
#pragma unroll
  for (int m = 1; m < 64; m <<= 1) { s += __shfl_xor(s, m); s2 += __shfl_xor(s2, m); }
  __shared__ float ps[8];
  int w = tid >> 6;
  if ((tid & 63) == 0) { ps[w] = s; ps[4 + w] = s2; }
  __syncthreads();
  s  = ps[0] + ps[1] + ps[2] + ps[3];
  s2 = ps[4] + ps[5] + ps[6] + ps[7];
  float mu   = s * (1.0f / 1024.0f);
  float var  = fmaxf(s2 * (1.0f / 1024.0f) - mu * mu, 0.f);
  float rstd = rsqrtf(var + 1e-5f);
  float4 gv = reinterpret_cast<const float4*>(g)[tid];
  float4 bv = reinterpret_cast<const float4*>(b)[tid];
  ushort4 o;
  o.x = f2b((v.x - mu) * rstd * gv.x + bv.x);
  o.y = f2b((v.y - mu) * rstd * gv.y + bv.y);
  o.z = f2b((v.z - mu) * rstd * gv.z + bv.z);
  o.w = f2b((v.w - mu) * rstd * gv.w + bv.w);
  reinterpret_cast<ushort4*>(y + (size_t)row * 1024)[tid] = o;
}

// ---- GEMM: C[M][N] = A[M][K] (bf16) * BT[N][K]^T (bf16) + bias, fused epilogue ----
// m97 structure: 128x128 tile, BK=32, global_load_lds width-16 staging, 2-barrier loop.
enum { EPI_QKV = 0, EPI_RESID = 1, EPI_GELU = 2 };

template <int EPI>
__global__ __launch_bounds__(256) void k_gemm(
    const unsigned short* __restrict__ A, const unsigned short* __restrict__ BT,
    const float* __restrict__ bias, int M, int N, int K,
    float* __restrict__ outf, const float* __restrict__ resid,
    unsigned short* __restrict__ outb,
    unsigned short* __restrict__ qb, unsigned short* __restrict__ kb,
    unsigned short* __restrict__ vb) {
  __shared__ __align__(16) unsigned short As[128][32];
  __shared__ __align__(16) unsigned short Bs[128][32];
  int m0 = blockIdx.y * 128, n0 = blockIdx.x * 128;
  int tid = threadIdx.x;
  int lane = tid & 63, wid = tid >> 6;
  int wr = wid >> 1, wc = wid & 1;
  int l15 = lane & 15, g = lane >> 4;
  // staging: wave wid fills rows [wid*32, wid*32+32) of As and Bs.
  // One gl16 instr = 64 lanes x 16B = 16 rows; lane i -> row +(i>>2), k-col (i&3)*8.
  int srow = wid * 32 + (lane >> 2);
  int skol = (lane & 3) * 8;
  f32x4 acc[4][4] = {};
  for (int k0 = 0; k0 < K; k0 += 32) {
    __syncthreads();
    gl16(A  + (size_t)(m0 + srow) * K + k0 + skol,      &As[wid * 32][0]);
    gl16(A  + (size_t)(m0 + srow + 16) * K + k0 + skol, &As[wid * 32 + 16][0]);
    gl16(BT + (size_t)(n0 + srow) * K + k0 + skol,      &Bs[wid * 32][0]);
    gl16(BT + (size_t)(n0 + srow + 16) * K + k0 + skol, &Bs[wid * 32 + 16][0]);
    __syncthreads();
    short8 af[4], bfr[4];
#pragma unroll
    for (int i = 0; i < 4; ++i)
      af[i] = *reinterpret_cast<const short8*>(&As[wr * 64 + i * 16 + l15][g * 8]);
#pragma unroll
    for (int i = 0; i < 4; ++i)
      bfr[i] = *reinterpret_cast<const short8*>(&Bs[wc * 64 + i * 16 + l15][g * 8]);
#pragma unroll
    for (int mi = 0; mi < 4; ++mi)
#pragma unroll
      for (int ni = 0; ni < 4; ++ni)
        acc[mi][ni] = __builtin_amdgcn_mfma_f32_16x16x32_bf16(af[mi], bfr[ni], acc[mi][ni], 0, 0, 0);
  }
#pragma unroll
  for (int mi = 0; mi < 4; ++mi) {
#pragma unroll
    for (int ni = 0; ni < 4; ++ni) {
      int row0 = m0 + wr * 64 + mi * 16 + g * 4;
      int col  = n0 + wc * 64 + ni * 16 + l15;
      float bcol = bias[col];
#pragma unroll
      for (int j = 0; j < 4; ++j) {
        int r = row0 + j;
        float vv = acc[mi][ni][j] + bcol;
        if (EPI == EPI_QKV) {
          int which = col >> 10;
          int hc = col & 1023;
          int h = hc >> 6, d = hc & 63;
          int bb = r >> 11, ss = r & 2047;
          size_t idx = (((size_t)(bb * 16 + h)) * 2048 + ss) * 64 + d;
          unsigned short bv_ = f2b(vv);
          if (which == 0)      qb[idx] = bv_;
          else if (which == 1) kb[idx] = bv_;
          else                 vb[idx] = bv_;
        } else if (EPI == EPI_RESID) {
          size_t idx = (size_t)r * N + col;
          outf[idx] = vv + resid[idx];
        } else {
          float ge = 0.5f * vv * (1.0f + erff(vv * 0.70710678118654752f));
          outb[(size_t)r * N + col] = f2b(ge);
        }
      }
    }
  }
}

// ---- flash attention: grid (16, 32), 4 waves x 32 q-rows, KVBLK=64 ----
__global__ __launch_bounds__(256) void k_attn(
    const unsigned short* __restrict__ qb, const unsigned short* __restrict__ kb,
    const unsigned short* __restrict__ vt, unsigned short* __restrict__ attn_out) {
  // P buffer: per-wave, per-qi [16 rows][64 cols] bf16, 16B-chunk XOR swizzle
  __shared__ __align__(16) unsigned short Plds[4][2][16][64];
  int bh = blockIdx.y;
  int b = bh >> 4, h = bh & 15;
  int tid = threadIdx.x;
  int lane = tid & 63, wid = tid >> 6;
  int l15 = lane & 15, g = lane >> 4;
  int q0 = blockIdx.x * 128 + wid * 32;
  const unsigned short* Qb = qb + (size_t)bh * 2048 * 64;
  const unsigned short* Kb = kb + (size_t)bh * 2048 * 64;
  const unsigned short* Vt = vt + (size_t)bh * 64 * 2048;
  short8 qf[2][2];
#pragma unroll
  for (int qi = 0; qi < 2; ++qi)
#pragma unroll
    for (int c = 0; c < 2; ++c)
      qf[qi][c] = *reinterpret_cast<const short8*>(&Qb[(size_t)(q0 + qi * 16 + l15) * 64 + c * 32 + g * 8]);
  float mj[2][4], lj[2][4];
  f32x4 o[2][4] = {};
#pragma unroll
  for (int qi = 0; qi < 2; ++qi)
#pragma unroll
    for (int j = 0; j < 4; ++j) { mj[qi][j] = -1e30f; lj[qi][j] = 0.f; }

  for (int t0 = 0; t0 < 2048; t0 += 64) {
    // K fragments (64 keys x 64 d)
    short8 kf[4][2];
#pragma unroll
    for (int kbk = 0; kbk < 4; ++kbk)
#pragma unroll
      for (int c = 0; c < 2; ++c)
        kf[kbk][c] = *reinterpret_cast<const short8*>(&Kb[(size_t)(t0 + kbk * 16 + l15) * 64 + c * 32 + g * 8]);
    // QK^T
    f32x4 sc[2][4] = {};
#pragma unroll
    for (int qi = 0; qi < 2; ++qi)
#pragma unroll
      for (int kbk = 0; kbk < 4; ++kbk) {
        sc[qi][kbk] = __builtin_amdgcn_mfma_f32_16x16x32_bf16(qf[qi][0], kf[kbk][0], sc[qi][kbk], 0, 0, 0);
        sc[qi][kbk] = __builtin_amdgcn_mfma_f32_16x16x32_bf16(qf[qi][1], kf[kbk][1], sc[qi][kbk], 0, 0, 0);
      }
    // online softmax; lane holds keys {l15+16*kbk} for q-row g*4+j of frag qi
#pragma unroll
    for (int qi = 0; qi < 2; ++qi) {
#pragma unroll
      for (int j = 0; j < 4; ++j) {
        float s0 = sc[qi][0][j] * 0.125f;
        float s1 = sc[qi][1][j] * 0.125f;
        float s2 = sc[qi][2][j] * 0.125f;
        float s3 = sc[qi][3][j] * 0.125f;
        float mx = fmaxf(fmaxf(s0, s1), fmaxf(s2, s3));
#pragma unroll
        for (int mk = 1; mk < 16; mk <<= 1) mx = fmaxf(mx, __shfl_xor(mx, mk));
        float mnew = fmaxf(mj[qi][j], mx);
        float efac = __expf(mj[qi][j] - mnew);
        float p0 = __expf(s0 - mnew);
        float p1 = __expf(s1 - mnew);
        float p2 = __expf(s2 - mnew);
        float p3 = __expf(s3 - mnew);
        float ts = (p0 + p1) + (p2 + p3);
#pragma unroll
        for (int mk = 1; mk < 16; mk <<= 1) ts += __shfl_xor(ts, mk);
        lj[qi][j] = lj[qi][j] * efac + ts;
        mj[qi][j] = mnew;
#pragma unroll
        for (int ct = 0; ct < 4; ++ct) o[qi][ct][j] *= efac;
        int row = g * 4 + j;
        unsigned short* pr = &Plds[wid][qi][row][0];
        float pv[4] = {p0, p1, p2, p3};
#pragma unroll
        for (int kbk = 0; kbk < 4; ++kbk) {
          int col = l15 + kbk * 16;
          pr[(((col >> 3) ^ (row & 7)) << 3) + (col & 7)] = f2b(pv[kbk]);
        }
      }
    }
    // PV: O[q][d] += P[q][t] * VT[d][t]
#pragma unroll
    for (int qi = 0; qi < 2; ++qi) {
      short8 pf[2];
#pragma unroll
      for (int tc = 0; tc < 2; ++tc)
        pf[tc] = *reinterpret_cast<const short8*>(&Plds[wid][qi][l15][((tc * 4 + g) ^ (l15 & 7)) << 3]);
#pragma unroll
      for (int ct = 0; ct < 4; ++ct) {
#pragma unroll
        for (int tc = 0; tc < 2; ++tc) {
          short8 vf = *reinterpret_cast<const short8*>(&Vt[(size_t)(ct * 16 + l15) * 2048 + t0 + tc * 32 + g * 8]);
          o[qi][ct] = __builtin_amdgcn_mfma_f32_16x16x32_bf16(pf[tc], vf, o[qi][ct], 0, 0, 0);
        }
      }
    }
  }
#pragma unroll
  for (int qi = 0; qi < 2; ++qi)
#pragma unroll
    for (int j = 0; j < 4; ++j) {
      float inv = 1.0f / lj[qi][j];
      int s = q0 + qi * 16 + g * 4 + j;
      size_t t = (size_t)b * 2048 + s;
#pragma unroll
      for (int ct = 0; ct < 4; ++ct)
        attn_out[t * 1024 + h * 64 + ct * 16 + l15] = f2b(o[qi][ct][j] * inv);
    }
}

extern "C" void kernel_launch(void* const* d_in, const int* in_sizes, int n_in,
                              void* d_out, int out_size, void* d_ws, size_t ws_size,
                              hipStream_t stream) {
  (void)in_sizes; (void)n_in; (void)out_size; (void)ws_size;
  const float* x      = (const float*)d_in[0];
  const float* ln1_g  = (const float*)d_in[1];
  const float* ln1_b  = (const float*)d_in[2];
  const float* w_qkv  = (const float*)d_in[3];
  const float* b_qkv  = (const float*)d_in[4];
  const float* w_ao   = (const float*)d_in[5];
  const float* b_ao   = (const float*)d_in[6];
  const float* ln2_g  = (const float*)d_in[7];
  const float* ln2_b  = (const float*)d_in[8];
  const float* w_fc   = (const float*)d_in[9];
  const float* b_fc   = (const float*)d_in[10];
  const float* w_proj = (const float*)d_in[11];
  const float* b_proj = (const float*)d_in[12];
  float* out = (float*)d_out;

  char* ws = (char*)d_ws;
  size_t o = 0;
  auto nxt = [&](size_t bytes) { void* p = ws + o; o += (bytes + 255) & ~(size_t)255; return p; };
  unsigned short* wT_qkv  = (unsigned short*)nxt((size_t)3072 * 1024 * 2);
  unsigned short* wT_ao   = (unsigned short*)nxt((size_t)1024 * 1024 * 2);
  unsigned short* wT_fc   = (unsigned short*)nxt((size_t)4096 * 1024 * 2);
  unsigned short* wT_proj = (unsigned short*)nxt((size_t)1024 * 4096 * 2);
  unsigned short* h_ln    = (unsigned short*)nxt((size_t)4096 * 1024 * 2);
  unsigned short* qbuf    = (unsigned short*)nxt((size_t)4096 * 1024 * 2);
  unsigned short* kbuf    = (unsigned short*)nxt((size_t)4096 * 1024 * 2);
  unsigned short* vbuf    = (unsigned short*)nxt((size_t)4096 * 1024 * 2);
  unsigned short* vtb     = (unsigned short*)nxt((size_t)4096 * 1024 * 2);
  float*          out1    = (float*)nxt((size_t)4096 * 1024 * 4);
  unsigned short* fc_buf  = qbuf;  // reuse qkv region (33.5 MB) after attention
  unsigned short* attn_o  = vbuf;  // reuse vbuf after V-transpose

  dim3 b32(32, 8, 1);
  k_tcvt<<<dim3(96, 32), b32, 0, stream>>>(w_qkv, wT_qkv, 1024, 3072);
  k_tcvt<<<dim3(32, 32), b32, 0, stream>>>(w_ao, wT_ao, 1024, 1024);
  k_tcvt<<<dim3(128, 32), b32, 0, stream>>>(w_fc, wT_fc, 1024, 4096);
  k_tcvt<<<dim3(32, 128), b32, 0, stream>>>(w_proj, wT_proj, 4096, 1024);

  k_ln<<<4096, 256, 0, stream>>>(x, ln1_g, ln1_b, h_ln);
  k_gemm<EPI_QKV><<<dim3(24, 32), 256, 0, stream>>>(h_ln, wT_qkv, b_qkv, 4096, 3072, 1024,
                                                    nullptr, nullptr, nullptr, qbuf, kbuf, vbuf);
  k_tv<<<dim3(2, 64, 32), b32, 0, stream>>>(vbuf, vtb);
  k_attn<<<dim3(16, 32), 256, 0, stream>>>(qbuf, kbuf, vtb, attn_o);
  k_gemm<EPI_RESID><<<dim3(8, 32), 256, 0, stream>>>(attn_o, wT_ao, b_ao, 4096, 1024, 1024,
                                                     out1, x, nullptr, nullptr, nullptr, nullptr);
  k_ln<<<4096, 256, 0, stream>>>(out1, ln2_g, ln2_b, h_ln);
  k_gemm<EPI_GELU><<<dim3(32, 32), 256, 0, stream>>>(h_ln, wT_fc, b_fc, 4096, 4096, 1024,
                                                     nullptr, nullptr, fc_buf, nullptr, nullptr, nullptr);
  k_gemm<EPI_RESID><<<dim3(8, 32), 256, 0, stream>>>(fc_buf, wT_proj, b_proj, 4096, 1024, 4096,
                                                     out, out1, nullptr, nullptr, nullptr, nullptr);
}

// Round 3
// 324.389 us; speedup vs baseline: 1.4488x; 1.1933x over previous
//
#include <hip/hip_runtime.h>
#include <hip/hip_bf16.h>

using short8 = __attribute__((ext_vector_type(8))) short;
using f32x4  = __attribute__((ext_vector_type(4))) float;

#define DEV __device__ __forceinline__

DEV unsigned short f2b(float f) {
  union { float f; unsigned u; } cv; cv.f = f;
  unsigned r = (cv.u + 0x7fffu + ((cv.u >> 16) & 1u)) >> 16;
  return (unsigned short)r;
}

typedef const __attribute__((address_space(1))) unsigned int* gp1;
typedef __attribute__((address_space(3))) unsigned int* lp3;
DEV void gl16(const void* g, void* l) {
  __builtin_amdgcn_global_load_lds((gp1)g, (lp3)l, 16, 0, 0);
}

// ---- transpose + convert: fp32 src[K][N] -> bf16 dst[N][K] ----
__global__ void k_tcvt(const float* __restrict__ src, unsigned short* __restrict__ dst,
                       int K, int N) {
  __shared__ float tile[32][33];
  int n0 = blockIdx.x * 32, k0 = blockIdx.y * 32;
  int tx = threadIdx.x, ty = threadIdx.y;
#pragma unroll
  for (int j = 0; j < 4; ++j)
    tile[ty + j * 8][tx] = src[(size_t)(k0 + ty + j * 8) * N + (n0 + tx)];
  __syncthreads();
#pragma unroll
  for (int j = 0; j < 4; ++j)
    dst[(size_t)(n0 + ty + j * 8) * K + (k0 + tx)] = f2b(tile[tx][ty + j * 8]);
}

// ---- bf16 transpose: src[BH][2048][64] -> dst[BH][64][2048] ----
__global__ void k_tv(const unsigned short* __restrict__ src, unsigned short* __restrict__ dst) {
  __shared__ unsigned short tile[32][33];
  int d0 = blockIdx.x * 32, s0 = blockIdx.y * 32;
  size_t base = (size_t)blockIdx.z * 2048 * 64;
  int tx = threadIdx.x, ty = threadIdx.y;
#pragma unroll
  for (int j = 0; j < 4; ++j)
    tile[ty + j * 8][tx] = src[base + (size_t)(s0 + ty + j * 8) * 64 + (d0 + tx)];
  __syncthreads();
#pragma unroll
  for (int j = 0; j < 4; ++j)
    dst[base + (size_t)(d0 + ty + j * 8) * 2048 + (s0 + tx)] = tile[tx][ty + j * 8];
}

// ---- LayerNorm: fp32 in [rows][1024] -> bf16 out ----
__global__ __launch_bounds__(256) void k_ln(const float* __restrict__ x,
                                            const float* __restrict__ g,
                                            const float* __restrict__ b,
                                            unsigned short* __restrict__ y) {
  int row = blockIdx.x, tid = threadIdx.x;
  float4 v = reinterpret_cast<const float4*>(x + (size_t)row * 1024)[tid];
  float s  = v.x + v.y + v.z + v.w;
  float s2 = v.x * v.x + v.y * v.y + v.z * v.z + v.w * v.w;
#pragma unroll
  for (int m = 1; m < 64; m <<= 1) { s += __shfl_xor(s, m); s2 += __shfl_xor(s2, m); }
  __shared__ float ps[8];
  int w = tid >> 6;
  if ((tid & 63) == 0) { ps[w] = s; ps[4 + w] = s2; }
  __syncthreads();
  s  = ps[0] + ps[1] + ps[2] + ps[3];
  s2 = ps[4] + ps[5] + ps[6] + ps[7];
  float mu   = s * (1.0f / 1024.0f);
  float var  = fmaxf(s2 * (1.0f / 1024.0f) - mu * mu, 0.f);
  float rstd = rsqrtf(var + 1e-5f);
  float4 gv = reinterpret_cast<const float4*>(g)[tid];
  float4 bv = reinterpret_cast<const float4*>(b)[tid];
  ushort4 o;
  o.x = f2b((v.x - mu) * rstd * gv.x + bv.x);
  o.y = f2b((v.y - mu) * rstd * gv.y + bv.y);
  o.z = f2b((v.z - mu) * rstd * gv.z + bv.z);
  o.w = f2b((v.w - mu) * rstd * gv.w + bv.w);
  reinterpret_cast<ushort4*>(y + (size_t)row * 1024)[tid] = o;
}

// ---- GEMM: C[M][N] = A[M][K] (bf16) * BT[N][K]^T (bf16) + bias, fused epilogue ----
enum { EPI_QKV = 0, EPI_RESID = 1, EPI_GELU = 2 };

template <int EPI>
__global__ __launch_bounds__(256) void k_gemm(
    const unsigned short* __restrict__ A, const unsigned short* __restrict__ BT,
    const float* __restrict__ bias, int M, int N, int K,
    float* __restrict__ outf, const float* __restrict__ resid,
    unsigned short* __restrict__ outb,
    unsigned short* __restrict__ qb, unsigned short* __restrict__ kb,
    unsigned short* __restrict__ vb) {
  __shared__ __align__(16) unsigned short As[128][32];
  __shared__ __align__(16) unsigned short Bs[128][32];
  int m0 = blockIdx.y * 128, n0 = blockIdx.x * 128;
  int tid = threadIdx.x;
  int lane = tid & 63, wid = tid >> 6;
  int wr = wid >> 1, wc = wid & 1;
  int l15 = lane & 15, g = lane >> 4;
  int srow = wid * 32 + (lane >> 2);
  int skol = (lane & 3) * 8;
  f32x4 acc[4][4] = {};
  for (int k0 = 0; k0 < K; k0 += 32) {
    __syncthreads();
    gl16(A  + (size_t)(m0 + srow) * K + k0 + skol,      &As[wid * 32][0]);
    gl16(A  + (size_t)(m0 + srow + 16) * K + k0 + skol, &As[wid * 32 + 16][0]);
    gl16(BT + (size_t)(n0 + srow) * K + k0 + skol,      &Bs[wid * 32][0]);
    gl16(BT + (size_t)(n0 + srow + 16) * K + k0 + skol, &Bs[wid * 32 + 16][0]);
    __syncthreads();
    short8 af[4], bfr[4];
#pragma unroll
    for (int i = 0; i < 4; ++i)
      af[i] = *reinterpret_cast<const short8*>(&As[wr * 64 + i * 16 + l15][g * 8]);
#pragma unroll
    for (int i = 0; i < 4; ++i)
      bfr[i] = *reinterpret_cast<const short8*>(&Bs[wc * 64 + i * 16 + l15][g * 8]);
#pragma unroll
    for (int mi = 0; mi < 4; ++mi)
#pragma unroll
      for (int ni = 0; ni < 4; ++ni)
        acc[mi][ni] = __builtin_amdgcn_mfma_f32_16x16x32_bf16(af[mi], bfr[ni], acc[mi][ni], 0, 0, 0);
  }
#pragma unroll
  for (int mi = 0; mi < 4; ++mi) {
#pragma unroll
    for (int ni = 0; ni < 4; ++ni) {
      int row0 = m0 + wr * 64 + mi * 16 + g * 4;
      int col  = n0 + wc * 64 + ni * 16 + l15;
      float bcol = bias[col];
#pragma unroll
      for (int j = 0; j < 4; ++j) {
        int r = row0 + j;
        float vv = acc[mi][ni][j] + bcol;
        if (EPI == EPI_QKV) {
          int which = col >> 10;
          int hc = col & 1023;
          int h = hc >> 6, d = hc & 63;
          int bb = r >> 11, ss = r & 2047;
          size_t idx = (((size_t)(bb * 16 + h)) * 2048 + ss) * 64 + d;
          // Q pre-scaled by SCALE*log2(e) so attention softmax runs in exp2 domain
          unsigned short bv_ = f2b(which == 0 ? vv * 0.18033688011112042f : vv);
          if (which == 0)      qb[idx] = bv_;
          else if (which == 1) kb[idx] = bv_;
          else                 vb[idx] = bv_;
        } else if (EPI == EPI_RESID) {
          size_t idx = (size_t)r * N + col;
          outf[idx] = vv + resid[idx];
        } else {
          float ge = 0.5f * vv * (1.0f + erff(vv * 0.70710678118654752f));
          outb[(size_t)r * N + col] = f2b(ge);
        }
      }
    }
  }
}

// ---- flash attention: grid (32, 32), 4 waves x 16 q-rows, KVBLK=64 ----
// swapped QK^T (mfma(K,Q)) -> lane-local row softmax in exp2 domain.
__global__ __launch_bounds__(256) void k_attn(
    const unsigned short* __restrict__ qb, const unsigned short* __restrict__ kb,
    const unsigned short* __restrict__ vt, unsigned short* __restrict__ attn_out) {
  __shared__ __align__(16) unsigned short Ks[64][64];   // [key][d], chunk-swizzled
  __shared__ __align__(16) unsigned short Vs[64][64];   // [d][key], chunk-swizzled
  __shared__ __align__(16) unsigned short Plds[4][16][72];  // per-wave P, padded
  int bh = blockIdx.y;
  int b = bh >> 4, h = bh & 15;
  int tid = threadIdx.x;
  int lane = tid & 63, wid = tid >> 6;
  int l15 = lane & 15, g = lane >> 4;
  int q0 = blockIdx.x * 64 + wid * 16;
  const unsigned short* Qb = qb + (size_t)bh * 2048 * 64;
  const unsigned short* Kb = kb + (size_t)bh * 2048 * 64;
  const unsigned short* Vt = vt + (size_t)bh * 64 * 2048;
  short8 qf0 = *reinterpret_cast<const short8*>(&Qb[(size_t)(q0 + l15) * 64 + g * 8]);
  short8 qf1 = *reinterpret_cast<const short8*>(&Qb[(size_t)(q0 + l15) * 64 + 32 + g * 8]);
  float mj = -1e30f, lj = 0.f;
  f32x4 o[4] = {};
  int sr  = wid * 16 + (lane >> 3);          // staged row (this wave: 16 rows)
  int scn = (lane & 7) ^ (sr & 7);           // pre-swizzled source chunk
  int swl = l15 & 7;                         // read-side swizzle key
  for (int t0 = 0; t0 < 2048; t0 += 64) {
    __syncthreads();
    gl16(Kb + (size_t)(t0 + sr) * 64 + scn * 8,       &Ks[wid * 16][0]);
    gl16(Kb + (size_t)(t0 + sr + 8) * 64 + scn * 8,   &Ks[wid * 16 + 8][0]);
    gl16(Vt + (size_t)sr * 2048 + t0 + scn * 8,       &Vs[wid * 16][0]);
    gl16(Vt + (size_t)(sr + 8) * 2048 + t0 + scn * 8, &Vs[wid * 16 + 8][0]);
    __syncthreads();
    // QK^T swapped: C[row=key][col=q]
    f32x4 scv[4];
#pragma unroll
    for (int kk = 0; kk < 4; ++kk) {
      short8 kf0 = *reinterpret_cast<const short8*>(&Ks[kk * 16 + l15][(g ^ swl) * 8]);
      short8 kf1 = *reinterpret_cast<const short8*>(&Ks[kk * 16 + l15][((4 + g) ^ swl) * 8]);
      f32x4 z = {};
      z = __builtin_amdgcn_mfma_f32_16x16x32_bf16(kf0, qf0, z, 0, 0, 0);
      scv[kk] = __builtin_amdgcn_mfma_f32_16x16x32_bf16(kf1, qf1, z, 0, 0, 0);
    }
    // lane-local softmax for q = l15 (keys: kk*16 + g*4 + j), exp2 domain
    float mx = -1e30f;
#pragma unroll
    for (int kk = 0; kk < 4; ++kk)
#pragma unroll
      for (int j = 0; j < 4; ++j) mx = fmaxf(mx, scv[kk][j]);
    mx = fmaxf(mx, __shfl_xor(mx, 16));
    mx = fmaxf(mx, __shfl_xor(mx, 32));
    bool skip = __all(mx <= mj + 8.0f);
    float mnew = skip ? mj : fmaxf(mj, mx);
    float p[16];
    float ts = 0.f;
#pragma unroll
    for (int kk = 0; kk < 4; ++kk)
#pragma unroll
      for (int j = 0; j < 4; ++j) {
        float pv = __builtin_amdgcn_exp2f(scv[kk][j] - mnew);
        p[kk * 4 + j] = pv;
        ts += pv;
      }
    ts += __shfl_xor(ts, 16);
    ts += __shfl_xor(ts, 32);
    if (!skip) {
      float ef = __builtin_amdgcn_exp2f(mj - mnew);
      int sb = 20 * g;  // lane 16g + (4g+j) holds state for o-row q'=4g+j
      float e0 = __shfl(ef, sb + 0), e1 = __shfl(ef, sb + 1);
      float e2 = __shfl(ef, sb + 2), e3 = __shfl(ef, sb + 3);
#pragma unroll
      for (int ct = 0; ct < 4; ++ct) {
        o[ct][0] *= e0; o[ct][1] *= e1; o[ct][2] *= e2; o[ct][3] *= e3;
      }
      lj = lj * ef + ts;
      mj = mnew;
    } else {
      lj += ts;
    }
    // P -> bf16 packed, write rows [q=l15][key]
#pragma unroll
    for (int kk = 0; kk < 4; ++kk) {
      unsigned r0, r1;
      asm("v_cvt_pk_bf16_f32 %0, %1, %2" : "=v"(r0) : "v"(p[kk * 4 + 0]), "v"(p[kk * 4 + 1]));
      asm("v_cvt_pk_bf16_f32 %0, %1, %2" : "=v"(r1) : "v"(p[kk * 4 + 2]), "v"(p[kk * 4 + 3]));
      unsigned long long w = (unsigned long long)r0 | ((unsigned long long)r1 << 32);
      *reinterpret_cast<unsigned long long*>(&Plds[wid][l15][kk * 16 + g * 4]) = w;
    }
    // PV: O[q][d] += P[q][t] * V[t][d]
    short8 pf0 = *reinterpret_cast<const short8*>(&Plds[wid][l15][g * 8]);
    short8 pf1 = *reinterpret_cast<const short8*>(&Plds[wid][l15][32 + g * 8]);
#pragma unroll
    for (int ct = 0; ct < 4; ++ct) {
      short8 vf0 = *reinterpret_cast<const short8*>(&Vs[ct * 16 + l15][(g ^ swl) * 8]);
      short8 vf1 = *reinterpret_cast<const short8*>(&Vs[ct * 16 + l15][((4 + g) ^ swl) * 8]);
      o[ct] = __builtin_amdgcn_mfma_f32_16x16x32_bf16(pf0, vf0, o[ct], 0, 0, 0);
      o[ct] = __builtin_amdgcn_mfma_f32_16x16x32_bf16(pf1, vf1, o[ct], 0, 0, 0);
    }
  }
  float invq = 1.0f / lj;
  int sb = 20 * g;
  float i0 = __shfl(invq, sb + 0), i1 = __shfl(invq, sb + 1);
  float i2 = __shfl(invq, sb + 2), i3 = __shfl(invq, sb + 3);
  float iv[4] = {i0, i1, i2, i3};
#pragma unroll
  for (int j = 0; j < 4; ++j) {
    size_t t = (size_t)b * 2048 + (q0 + g * 4 + j);
#pragma unroll
    for (int ct = 0; ct < 4; ++ct)
      attn_out[t * 1024 + h * 64 + ct * 16 + l15] = f2b(o[ct][j] * iv[j]);
  }
}

extern "C" void kernel_launch(void* const* d_in, const int* in_sizes, int n_in,
                              void* d_out, int out_size, void* d_ws, size_t ws_size,
                              hipStream_t stream) {
  (void)in_sizes; (void)n_in; (void)out_size; (void)ws_size;
  const float* x      = (const float*)d_in[0];
  const float* ln1_g  = (const float*)d_in[1];
  const float* ln1_b  = (const float*)d_in[2];
  const float* w_qkv  = (const float*)d_in[3];
  const float* b_qkv  = (const float*)d_in[4];
  const float* w_ao   = (const float*)d_in[5];
  const float* b_ao   = (const float*)d_in[6];
  const float* ln2_g  = (const float*)d_in[7];
  const float* ln2_b  = (const float*)d_in[8];
  const float* w_fc   = (const float*)d_in[9];
  const float* b_fc   = (const float*)d_in[10];
  const float* w_proj = (const float*)d_in[11];
  const float* b_proj = (const float*)d_in[12];
  float* out = (float*)d_out;

  char* ws = (char*)d_ws;
  size_t o = 0;
  auto nxt = [&](size_t bytes) { void* p = ws + o; o += (bytes + 255) & ~(size_t)255; return p; };
  unsigned short* wT_qkv  = (unsigned short*)nxt((size_t)3072 * 1024 * 2);
  unsigned short* wT_ao   = (unsigned short*)nxt((size_t)1024 * 1024 * 2);
  unsigned short* wT_fc   = (unsigned short*)nxt((size_t)4096 * 1024 * 2);
  unsigned short* wT_proj = (unsigned short*)nxt((size_t)1024 * 4096 * 2);
  unsigned short* h_ln    = (unsigned short*)nxt((size_t)4096 * 1024 * 2);
  unsigned short* qbuf    = (unsigned short*)nxt((size_t)4096 * 1024 * 2);
  unsigned short* kbuf    = (unsigned short*)nxt((size_t)4096 * 1024 * 2);
  unsigned short* vbuf    = (unsigned short*)nxt((size_t)4096 * 1024 * 2);
  unsigned short* vtb     = (unsigned short*)nxt((size_t)4096 * 1024 * 2);
  float*          out1    = (float*)nxt((size_t)4096 * 1024 * 4);
  unsigned short* fc_buf  = qbuf;  // reuse qkv region after attention
  unsigned short* attn_o  = vbuf;  // reuse vbuf after V-transpose

  dim3 b32(32, 8, 1);
  k_tcvt<<<dim3(96, 32), b32, 0, stream>>>(w_qkv, wT_qkv, 1024, 3072);
  k_tcvt<<<dim3(32, 32), b32, 0, stream>>>(w_ao, wT_ao, 1024, 1024);
  k_tcvt<<<dim3(128, 32), b32, 0, stream>>>(w_fc, wT_fc, 1024, 4096);
  k_tcvt<<<dim3(32, 128), b32, 0, stream>>>(w_proj, wT_proj, 4096, 1024);

  k_ln<<<4096, 256, 0, stream>>>(x, ln1_g, ln1_b, h_ln);
  k_gemm<EPI_QKV><<<dim3(24, 32), 256, 0, stream>>>(h_ln, wT_qkv, b_qkv, 4096, 3072, 1024,
                                                    nullptr, nullptr, nullptr, qbuf, kbuf, vbuf);
  k_tv<<<dim3(2, 64, 32), b32, 0, stream>>>(vbuf, vtb);
  k_attn<<<dim3(32, 32), 256, 0, stream>>>(qbuf, kbuf, vtb, attn_o);
  k_gemm<EPI_RESID><<<dim3(8, 32), 256, 0, stream>>>(attn_o, wT_ao, b_ao, 4096, 1024, 1024,
                                                     out1, x, nullptr, nullptr, nullptr, nullptr);
  k_ln<<<4096, 256, 0, stream>>>(out1, ln2_g, ln2_b, h_ln);
  k_gemm<EPI_GELU><<<dim3(32, 32), 256, 0, stream>>>(h_ln, wT_fc, b_fc, 4096, 4096, 1024,
                                                     nullptr, nullptr, fc_buf, nullptr, nullptr, nullptr);
  k_gemm<EPI_RESID><<<dim3(8, 32), 256, 0, stream>>>(fc_buf, wT_proj, b_proj, 4096, 1024, 4096,
                                                     out, out1, nullptr, nullptr, nullptr, nullptr);
}

// Round 4
// 300.149 us; speedup vs baseline: 1.5658x; 1.0808x over previous
//
#include <hip/hip_runtime.h>
#include <hip/hip_bf16.h>

using short8 = __attribute__((ext_vector_type(8))) short;
using f32x4  = __attribute__((ext_vector_type(4))) float;

#define DEV __device__ __forceinline__

DEV unsigned short f2b(float f) {
  union { float f; unsigned u; } cv; cv.f = f;
  unsigned r = (cv.u + 0x7fffu + ((cv.u >> 16) & 1u)) >> 16;
  return (unsigned short)r;
}

typedef const __attribute__((address_space(1))) unsigned int* gp1;
typedef __attribute__((address_space(3))) unsigned int* lp3;
DEV void gl16(const void* g, void* l) {
  __builtin_amdgcn_global_load_lds((gp1)g, (lp3)l, 16, 0, 0);
}

// ---- transpose + convert: fp32 src[K][N] -> bf16 dst[N][K] ----
__global__ void k_tcvt(const float* __restrict__ src, unsigned short* __restrict__ dst,
                       int K, int N) {
  __shared__ float tile[32][33];
  int n0 = blockIdx.x * 32, k0 = blockIdx.y * 32;
  int tx = threadIdx.x, ty = threadIdx.y;
#pragma unroll
  for (int j = 0; j < 4; ++j)
    tile[ty + j * 8][tx] = src[(size_t)(k0 + ty + j * 8) * N + (n0 + tx)];
  __syncthreads();
#pragma unroll
  for (int j = 0; j < 4; ++j)
    dst[(size_t)(n0 + ty + j * 8) * K + (k0 + tx)] = f2b(tile[tx][ty + j * 8]);
}

// ---- bf16 transpose: src[BH][2048][64] -> dst[BH][64][2048] ----
__global__ void k_tv(const unsigned short* __restrict__ src, unsigned short* __restrict__ dst) {
  __shared__ unsigned short tile[32][33];
  int d0 = blockIdx.x * 32, s0 = blockIdx.y * 32;
  size_t base = (size_t)blockIdx.z * 2048 * 64;
  int tx = threadIdx.x, ty = threadIdx.y;
#pragma unroll
  for (int j = 0; j < 4; ++j)
    tile[ty + j * 8][tx] = src[base + (size_t)(s0 + ty + j * 8) * 64 + (d0 + tx)];
  __syncthreads();
#pragma unroll
  for (int j = 0; j < 4; ++j)
    dst[base + (size_t)(d0 + ty + j * 8) * 2048 + (s0 + tx)] = tile[tx][ty + j * 8];
}

// ---- LayerNorm: fp32 in [rows][1024] -> bf16 out ----
__global__ __launch_bounds__(256) void k_ln(const float* __restrict__ x,
                                            const float* __restrict__ g,
                                            const float* __restrict__ b,
                                            unsigned short* __restrict__ y) {
  int row = blockIdx.x, tid = threadIdx.x;
  float4 v = reinterpret_cast<const float4*>(x + (size_t)row * 1024)[tid];
  float s  = v.x + v.y + v.z + v.w;
  float s2 = v.x * v.x + v.y * v.y + v.z * v.z + v.w * v.w;
#pragma unroll
  for (int m = 1; m < 64; m <<= 1) { s += __shfl_xor(s, m); s2 += __shfl_xor(s2, m); }
  __shared__ float ps[8];
  int w = tid >> 6;
  if ((tid & 63) == 0) { ps[w] = s; ps[4 + w] = s2; }
  __syncthreads();
  s  = ps[0] + ps[1] + ps[2] + ps[3];
  s2 = ps[4] + ps[5] + ps[6] + ps[7];
  float mu   = s * (1.0f / 1024.0f);
  float var  = fmaxf(s2 * (1.0f / 1024.0f) - mu * mu, 0.f);
  float rstd = rsqrtf(var + 1e-5f);
  float4 gv = reinterpret_cast<const float4*>(g)[tid];
  float4 bv = reinterpret_cast<const float4*>(b)[tid];
  ushort4 o;
  o.x = f2b((v.x - mu) * rstd * gv.x + bv.x);
  o.y = f2b((v.y - mu) * rstd * gv.y + bv.y);
  o.z = f2b((v.z - mu) * rstd * gv.z + bv.z);
  o.w = f2b((v.w - mu) * rstd * gv.w + bv.w);
  reinterpret_cast<ushort4*>(y + (size_t)row * 1024)[tid] = o;
}

enum { EPI_QKV = 0, EPI_RESID = 1, EPI_GELU = 2 };

// ---- GEMM 128x128 (m97 structure) + XCD swizzle ----
template <int EPI>
__global__ __launch_bounds__(256) void k_gemm(
    const unsigned short* __restrict__ A, const unsigned short* __restrict__ BT,
    const float* __restrict__ bias, int M, int N, int K,
    float* __restrict__ outf, const float* __restrict__ resid,
    unsigned short* __restrict__ outb) {
  __shared__ __align__(16) unsigned short As[128][32];
  __shared__ __align__(16) unsigned short Bs[128][32];
  int nx = gridDim.x, nwg = nx * gridDim.y;
  int w0 = blockIdx.y * nx + blockIdx.x;
  int id = (w0 & 7) * (nwg >> 3) + (w0 >> 3);
  int bx = id % nx, by = id / nx;
  int m0 = by * 128, n0 = bx * 128;
  int tid = threadIdx.x;
  int lane = tid & 63, wid = tid >> 6;
  int wr = wid >> 1, wc = wid & 1;
  int l15 = lane & 15, g = lane >> 4;
  int srow = wid * 32 + (lane >> 2);
  int skol = (lane & 3) * 8;
  f32x4 acc[4][4] = {};
  for (int k0 = 0; k0 < K; k0 += 32) {
    __syncthreads();
    gl16(A  + (size_t)(m0 + srow) * K + k0 + skol,      &As[wid * 32][0]);
    gl16(A  + (size_t)(m0 + srow + 16) * K + k0 + skol, &As[wid * 32 + 16][0]);
    gl16(BT + (size_t)(n0 + srow) * K + k0 + skol,      &Bs[wid * 32][0]);
    gl16(BT + (size_t)(n0 + srow + 16) * K + k0 + skol, &Bs[wid * 32 + 16][0]);
    __syncthreads();
    short8 af[4], bfr[4];
#pragma unroll
    for (int i = 0; i < 4; ++i)
      af[i] = *reinterpret_cast<const short8*>(&As[wr * 64 + i * 16 + l15][g * 8]);
#pragma unroll
    for (int i = 0; i < 4; ++i)
      bfr[i] = *reinterpret_cast<const short8*>(&Bs[wc * 64 + i * 16 + l15][g * 8]);
#pragma unroll
    for (int mi = 0; mi < 4; ++mi)
#pragma unroll
      for (int ni = 0; ni < 4; ++ni)
        acc[mi][ni] = __builtin_amdgcn_mfma_f32_16x16x32_bf16(af[mi], bfr[ni], acc[mi][ni], 0, 0, 0);
  }
#pragma unroll
  for (int mi = 0; mi < 4; ++mi) {
#pragma unroll
    for (int ni = 0; ni < 4; ++ni) {
      int row0 = m0 + wr * 64 + mi * 16 + g * 4;
      int col  = n0 + wc * 64 + ni * 16 + l15;
      float bcol = bias[col];
#pragma unroll
      for (int j = 0; j < 4; ++j) {
        int r = row0 + j;
        float vv = acc[mi][ni][j] + bcol;
        if (EPI == EPI_RESID) {
          size_t idx = (size_t)r * N + col;
          outf[idx] = vv + resid[idx];
        } else {
          float ge = 0.5f * vv * (1.0f + erff(vv * 0.70710678118654752f));
          outb[(size_t)r * N + col] = f2b(ge);
        }
      }
    }
  }
}

// ---- GEMM 256x256: 8 waves, BK=64, dbuf LDS, counted vmcnt, T2 swizzle, T5 ----
template <int EPI>
__global__ __launch_bounds__(512, 2) void k_gemm256(
    const unsigned short* __restrict__ A, const unsigned short* __restrict__ BT,
    const float* __restrict__ bias, int M, int N, int K,
    unsigned short* __restrict__ outb,
    unsigned short* __restrict__ qb, unsigned short* __restrict__ kb,
    unsigned short* __restrict__ vb) {
  __shared__ __align__(16) unsigned short Abuf[2][256][64];
  __shared__ __align__(16) unsigned short Bbuf[2][256][64];
  int nx = gridDim.x, nwg = nx * gridDim.y;
  int w0 = blockIdx.y * nx + blockIdx.x;
  int id = (w0 & 7) * (nwg >> 3) + (w0 >> 3);
  int bx = id % nx, by = id / nx;
  int m0 = by * 256, n0 = bx * 256;
  int tid = threadIdx.x;
  int lane = tid & 63, wid = tid >> 6;
  int wm = wid >> 2, wn = wid & 3;
  int l15 = lane & 15, g = lane >> 4;
  int swl = l15 & 7;
  // staging: wave wid owns rows [wid*32, wid*32+32) of each tile.
  // load i covers 8 rows; lane -> row + (lane>>3), physical chunk lane&7,
  // source chunk pre-swizzled: (lane&7) ^ (lane>>3)  (row&7 == lane>>3).
  int lrow = lane >> 3;
  int lchunk = (lane & 7) ^ lrow;
  const unsigned short* Asrc = A  + (size_t)(m0 + wid * 32 + lrow) * K + lchunk * 8;
  const unsigned short* Bsrc = BT + (size_t)(n0 + wid * 32 + lrow) * K + lchunk * 8;
  auto stage = [&](int buf, int k0) {
#pragma unroll
    for (int i = 0; i < 4; ++i)
      gl16(Asrc + k0 + (size_t)i * 8 * K, &Abuf[buf][wid * 32 + i * 8][0]);
#pragma unroll
    for (int i = 0; i < 4; ++i)
      gl16(Bsrc + k0 + (size_t)i * 8 * K, &Bbuf[buf][wid * 32 + i * 8][0]);
  };
  f32x4 acc[8][4] = {};
  int nt = K >> 6;
  stage(0, 0);
  stage(1, 64);
  asm volatile("s_waitcnt vmcnt(8)" ::: "memory");
  __builtin_amdgcn_sched_barrier(0);
  __builtin_amdgcn_s_barrier();
  int cur = 0;
  for (int t = 0; t < nt; ++t) {
    const unsigned short (*As)[64] = Abuf[cur];
    const unsigned short (*Bs)[64] = Bbuf[cur];
    short8 a0[8], b0[4], a1[8], b1[4];
#pragma unroll
    for (int mi = 0; mi < 8; ++mi)
      a0[mi] = *reinterpret_cast<const short8*>(&As[wm * 128 + mi * 16 + l15][(g ^ swl) * 8]);
#pragma unroll
    for (int ni = 0; ni < 4; ++ni)
      b0[ni] = *reinterpret_cast<const short8*>(&Bs[wn * 64 + ni * 16 + l15][(g ^ swl) * 8]);
    __builtin_amdgcn_s_setprio(1);
#pragma unroll
    for (int mi = 0; mi < 8; ++mi)
#pragma unroll
      for (int ni = 0; ni < 4; ++ni)
        acc[mi][ni] = __builtin_amdgcn_mfma_f32_16x16x32_bf16(a0[mi], b0[ni], acc[mi][ni], 0, 0, 0);
    __builtin_amdgcn_s_setprio(0);
#pragma unroll
    for (int mi = 0; mi < 8; ++mi)
      a1[mi] = *reinterpret_cast<const short8*>(&As[wm * 128 + mi * 16 + l15][((4 + g) ^ swl) * 8]);
#pragma unroll
    for (int ni = 0; ni < 4; ++ni)
      b1[ni] = *reinterpret_cast<const short8*>(&Bs[wn * 64 + ni * 16 + l15][((4 + g) ^ swl) * 8]);
    // all LDS reads of buf[cur] complete before any wave overwrites it
    asm volatile("s_waitcnt lgkmcnt(0)" ::: "memory");
    __builtin_amdgcn_sched_barrier(0);
    __builtin_amdgcn_s_barrier();
    __builtin_amdgcn_sched_barrier(0);
    if (t + 2 < nt) stage(cur, (t + 2) << 6);
    __builtin_amdgcn_s_setprio(1);
#pragma unroll
    for (int mi = 0; mi < 8; ++mi)
#pragma unroll
      for (int ni = 0; ni < 4; ++ni)
        acc[mi][ni] = __builtin_amdgcn_mfma_f32_16x16x32_bf16(a1[mi], b1[ni], acc[mi][ni], 0, 0, 0);
    __builtin_amdgcn_s_setprio(0);
    if (t + 2 < nt) {
      asm volatile("s_waitcnt vmcnt(8)" ::: "memory");  // tile t+1 fully landed
    } else if (t + 1 < nt) {
      asm volatile("s_waitcnt vmcnt(0)" ::: "memory");
    }
    __builtin_amdgcn_sched_barrier(0);
    __builtin_amdgcn_s_barrier();
    cur ^= 1;
  }
#pragma unroll
  for (int mi = 0; mi < 8; ++mi) {
#pragma unroll
    for (int ni = 0; ni < 4; ++ni) {
      int row0 = m0 + wm * 128 + mi * 16 + g * 4;
      int col  = n0 + wn * 64 + ni * 16 + l15;
      float bcol = bias[col];
#pragma unroll
      for (int j = 0; j < 4; ++j) {
        int r = row0 + j;
        float vv = acc[mi][ni][j] + bcol;
        if (EPI == EPI_QKV) {
          int which = col >> 10;
          int hc = col & 1023;
          int h = hc >> 6, d = hc & 63;
          int bb = r >> 11, ss = r & 2047;
          size_t idx = (((size_t)(bb * 16 + h)) * 2048 + ss) * 64 + d;
          unsigned short bv_ = f2b(which == 0 ? vv * 0.18033688011112042f : vv);
          if (which == 0)      qb[idx] = bv_;
          else if (which == 1) kb[idx] = bv_;
          else                 vb[idx] = bv_;
        } else {
          float ge = 0.5f * vv * (1.0f + erff(vv * 0.70710678118654752f));
          outb[(size_t)r * N + col] = f2b(ge);
        }
      }
    }
  }
}

// ---- flash attention: grid (32, 32), 4 waves x 16 q-rows, KVBLK=64 ----
__global__ __launch_bounds__(256) void k_attn(
    const unsigned short* __restrict__ qb, const unsigned short* __restrict__ kb,
    const unsigned short* __restrict__ vt, unsigned short* __restrict__ attn_out) {
  __shared__ __align__(16) unsigned short Ks[64][64];
  __shared__ __align__(16) unsigned short Vs[64][64];
  __shared__ __align__(16) unsigned short Plds[4][16][72];
  int bh = blockIdx.y;
  int b = bh >> 4, h = bh & 15;
  int tid = threadIdx.x;
  int lane = tid & 63, wid = tid >> 6;
  int l15 = lane & 15, g = lane >> 4;
  int q0 = blockIdx.x * 64 + wid * 16;
  const unsigned short* Qb = qb + (size_t)bh * 2048 * 64;
  const unsigned short* Kb = kb + (size_t)bh * 2048 * 64;
  const unsigned short* Vt = vt + (size_t)bh * 64 * 2048;
  short8 qf0 = *reinterpret_cast<const short8*>(&Qb[(size_t)(q0 + l15) * 64 + g * 8]);
  short8 qf1 = *reinterpret_cast<const short8*>(&Qb[(size_t)(q0 + l15) * 64 + 32 + g * 8]);
  float mj = -1e30f, lj = 0.f;
  f32x4 o[4] = {};
  int sr  = wid * 16 + (lane >> 3);
  int scn = (lane & 7) ^ (sr & 7);
  int swl = l15 & 7;
  for (int t0 = 0; t0 < 2048; t0 += 64) {
    __syncthreads();
    gl16(Kb + (size_t)(t0 + sr) * 64 + scn * 8,       &Ks[wid * 16][0]);
    gl16(Kb + (size_t)(t0 + sr + 8) * 64 + scn * 8,   &Ks[wid * 16 + 8][0]);
    gl16(Vt + (size_t)sr * 2048 + t0 + scn * 8,       &Vs[wid * 16][0]);
    gl16(Vt + (size_t)(sr + 8) * 2048 + t0 + scn * 8, &Vs[wid * 16 + 8][0]);
    __syncthreads();
    f32x4 scv[4];
#pragma unroll
    for (int kk = 0; kk < 4; ++kk) {
      short8 kf0 = *reinterpret_cast<const short8*>(&Ks[kk * 16 + l15][(g ^ swl) * 8]);
      short8 kf1 = *reinterpret_cast<const short8*>(&Ks[kk * 16 + l15][((4 + g) ^ swl) * 8]);
      f32x4 z = {};
      z = __builtin_amdgcn_mfma_f32_16x16x32_bf16(kf0, qf0, z, 0, 0, 0);
      scv[kk] = __builtin_amdgcn_mfma_f32_16x16x32_bf16(kf1, qf1, z, 0, 0, 0);
    }
    float mx = -1e30f;
#pragma unroll
    for (int kk = 0; kk < 4; ++kk)
#pragma unroll
      for (int j = 0; j < 4; ++j) mx = fmaxf(mx, scv[kk][j]);
    mx = fmaxf(mx, __shfl_xor(mx, 16));
    mx = fmaxf(mx, __shfl_xor(mx, 32));
    bool skip = __all(mx <= mj + 8.0f);
    float mnew = skip ? mj : fmaxf(mj, mx);
    float p[16];
    float ts = 0.f;
#pragma unroll
    for (int kk = 0; kk < 4; ++kk)
#pragma unroll
      for (int j = 0; j < 4; ++j) {
        float pv = __builtin_amdgcn_exp2f(scv[kk][j] - mnew);
        p[kk * 4 + j] = pv;
        ts += pv;
      }
    ts += __shfl_xor(ts, 16);
    ts += __shfl_xor(ts, 32);
    if (!skip) {
      float ef = __builtin_amdgcn_exp2f(mj - mnew);
      int sb = 20 * g;
      float e0 = __shfl(ef, sb + 0), e1 = __shfl(ef, sb + 1);
      float e2 = __shfl(ef, sb + 2), e3 = __shfl(ef, sb + 3);
#pragma unroll
      for (int ct = 0; ct < 4; ++ct) {
        o[ct][0] *= e0; o[ct][1] *= e1; o[ct][2] *= e2; o[ct][3] *= e3;
      }
      lj = lj * ef + ts;
      mj = mnew;
    } else {
      lj += ts;
    }
#pragma unroll
    for (int kk = 0; kk < 4; ++kk) {
      unsigned r0, r1;
      asm("v_cvt_pk_bf16_f32 %0, %1, %2" : "=v"(r0) : "v"(p[kk * 4 + 0]), "v"(p[kk * 4 + 1]));
      asm("v_cvt_pk_bf16_f32 %0, %1, %2" : "=v"(r1) : "v"(p[kk * 4 + 2]), "v"(p[kk * 4 + 3]));
      unsigned long long w = (unsigned long long)r0 | ((unsigned long long)r1 << 32);
      *reinterpret_cast<unsigned long long*>(&Plds[wid][l15][kk * 16 + g * 4]) = w;
    }
    short8 pf0 = *reinterpret_cast<const short8*>(&Plds[wid][l15][g * 8]);
    short8 pf1 = *reinterpret_cast<const short8*>(&Plds[wid][l15][32 + g * 8]);
#pragma unroll
    for (int ct = 0; ct < 4; ++ct) {
      short8 vf0 = *reinterpret_cast<const short8*>(&Vs[ct * 16 + l15][(g ^ swl) * 8]);
      short8 vf1 = *reinterpret_cast<const short8*>(&Vs[ct * 16 + l15][((4 + g) ^ swl) * 8]);
      o[ct] = __builtin_amdgcn_mfma_f32_16x16x32_bf16(pf0, vf0, o[ct], 0, 0, 0);
      o[ct] = __builtin_amdgcn_mfma_f32_16x16x32_bf16(pf1, vf1, o[ct], 0, 0, 0);
    }
  }
  float invq = 1.0f / lj;
  int sb = 20 * g;
  float i0 = __shfl(invq, sb + 0), i1 = __shfl(invq, sb + 1);
  float i2 = __shfl(invq, sb + 2), i3 = __shfl(invq, sb + 3);
  float iv[4] = {i0, i1, i2, i3};
#pragma unroll
  for (int j = 0; j < 4; ++j) {
    size_t t = (size_t)b * 2048 + (q0 + g * 4 + j);
#pragma unroll
    for (int ct = 0; ct < 4; ++ct)
      attn_out[t * 1024 + h * 64 + ct * 16 + l15] = f2b(o[ct][j] * iv[j]);
  }
}

extern "C" void kernel_launch(void* const* d_in, const int* in_sizes, int n_in,
                              void* d_out, int out_size, void* d_ws, size_t ws_size,
                              hipStream_t stream) {
  (void)in_sizes; (void)n_in; (void)out_size; (void)ws_size;
  const float* x      = (const float*)d_in[0];
  const float* ln1_g  = (const float*)d_in[1];
  const float* ln1_b  = (const float*)d_in[2];
  const float* w_qkv  = (const float*)d_in[3];
  const float* b_qkv  = (const float*)d_in[4];
  const float* w_ao   = (const float*)d_in[5];
  const float* b_ao   = (const float*)d_in[6];
  const float* ln2_g  = (const float*)d_in[7];
  const float* ln2_b  = (const float*)d_in[8];
  const float* w_fc   = (const float*)d_in[9];
  const float* b_fc   = (const float*)d_in[10];
  const float* w_proj = (const float*)d_in[11];
  const float* b_proj = (const float*)d_in[12];
  float* out = (float*)d_out;

  char* ws = (char*)d_ws;
  size_t o = 0;
  auto nxt = [&](size_t bytes) { void* p = ws + o; o += (bytes + 255) & ~(size_t)255; return p; };
  unsigned short* wT_qkv  = (unsigned short*)nxt((size_t)3072 * 1024 * 2);
  unsigned short* wT_ao   = (unsigned short*)nxt((size_t)1024 * 1024 * 2);
  unsigned short* wT_fc   = (unsigned short*)nxt((size_t)4096 * 1024 * 2);
  unsigned short* wT_proj = (unsigned short*)nxt((size_t)1024 * 4096 * 2);
  unsigned short* h_ln    = (unsigned short*)nxt((size_t)4096 * 1024 * 2);
  unsigned short* qbuf    = (unsigned short*)nxt((size_t)4096 * 1024 * 2);
  unsigned short* kbuf    = (unsigned short*)nxt((size_t)4096 * 1024 * 2);
  unsigned short* vbuf    = (unsigned short*)nxt((size_t)4096 * 1024 * 2);
  unsigned short* vtb     = (unsigned short*)nxt((size_t)4096 * 1024 * 2);
  float*          out1    = (float*)nxt((size_t)4096 * 1024 * 4);
  unsigned short* fc_buf  = qbuf;
  unsigned short* attn_o  = vbuf;

  dim3 b32(32, 8, 1);
  k_tcvt<<<dim3(96, 32), b32, 0, stream>>>(w_qkv, wT_qkv, 1024, 3072);
  k_tcvt<<<dim3(32, 32), b32, 0, stream>>>(w_ao, wT_ao, 1024, 1024);
  k_tcvt<<<dim3(128, 32), b32, 0, stream>>>(w_fc, wT_fc, 1024, 4096);
  k_tcvt<<<dim3(32, 128), b32, 0, stream>>>(w_proj, wT_proj, 4096, 1024);

  k_ln<<<4096, 256, 0, stream>>>(x, ln1_g, ln1_b, h_ln);
  k_gemm256<EPI_QKV><<<dim3(12, 16), 512, 0, stream>>>(h_ln, wT_qkv, b_qkv, 4096, 3072, 1024,
                                                       nullptr, qbuf, kbuf, vbuf);
  k_tv<<<dim3(2, 64, 32), b32, 0, stream>>>(vbuf, vtb);
  k_attn<<<dim3(32, 32), 256, 0, stream>>>(qbuf, kbuf, vtb, attn_o);
  k_gemm<EPI_RESID><<<dim3(8, 32), 256, 0, stream>>>(attn_o, wT_ao, b_ao, 4096, 1024, 1024,
                                                     out1, x, nullptr);
  k_ln<<<4096, 256, 0, stream>>>(out1, ln2_g, ln2_b, h_ln);
  k_gemm256<EPI_GELU><<<dim3(16, 16), 512, 0, stream>>>(h_ln, wT_fc, b_fc, 4096, 4096, 1024,
                                                        fc_buf, nullptr, nullptr, nullptr);
  k_gemm<EPI_RESID><<<dim3(8, 32), 256, 0, stream>>>(fc_buf, wT_proj, b_proj, 4096, 1024, 4096,
                                                     out, out1, nullptr);
}

// Round 5
// 257.832 us; speedup vs baseline: 1.8228x; 1.1641x over previous
//
#include <hip/hip_runtime.h>
#include <hip/hip_bf16.h>

using short8 = __attribute__((ext_vector_type(8))) short;
using f32x4  = __attribute__((ext_vector_type(4))) float;

#define DEV __device__ __forceinline__

DEV unsigned short f2b(float f) {
  union { float f; unsigned u; } cv; cv.f = f;
  unsigned r = (cv.u + 0x7fffu + ((cv.u >> 16) & 1u)) >> 16;
  return (unsigned short)r;
}

typedef const __attribute__((address_space(1))) unsigned int* gp1;
typedef __attribute__((address_space(3))) unsigned int* lp3;
DEV void gl16(const void* g, void* l) {
  __builtin_amdgcn_global_load_lds((gp1)g, (lp3)l, 16, 0, 0);
}

// ---- transpose + convert: fp32 src[K][N] -> bf16 dst[N][K] ----
__global__ void k_tcvt(const float* __restrict__ src, unsigned short* __restrict__ dst,
                       int K, int N) {
  __shared__ float tile[32][33];
  int n0 = blockIdx.x * 32, k0 = blockIdx.y * 32;
  int tx = threadIdx.x, ty = threadIdx.y;
#pragma unroll
  for (int j = 0; j < 4; ++j)
    tile[ty + j * 8][tx] = src[(size_t)(k0 + ty + j * 8) * N + (n0 + tx)];
  __syncthreads();
#pragma unroll
  for (int j = 0; j < 4; ++j)
    dst[(size_t)(n0 + ty + j * 8) * K + (k0 + tx)] = f2b(tile[tx][ty + j * 8]);
}

// ---- bf16 transpose: src[BH][2048][64] -> dst[BH][64][2048] ----
__global__ void k_tv(const unsigned short* __restrict__ src, unsigned short* __restrict__ dst) {
  __shared__ unsigned short tile[32][33];
  int d0 = blockIdx.x * 32, s0 = blockIdx.y * 32;
  size_t base = (size_t)blockIdx.z * 2048 * 64;
  int tx = threadIdx.x, ty = threadIdx.y;
#pragma unroll
  for (int j = 0; j < 4; ++j)
    tile[ty + j * 8][tx] = src[base + (size_t)(s0 + ty + j * 8) * 64 + (d0 + tx)];
  __syncthreads();
#pragma unroll
  for (int j = 0; j < 4; ++j)
    dst[base + (size_t)(d0 + ty + j * 8) * 2048 + (s0 + tx)] = tile[tx][ty + j * 8];
}

// ---- LayerNorm: fp32 in [rows][1024] -> bf16 out ----
__global__ __launch_bounds__(256) void k_ln(const float* __restrict__ x,
                                            const float* __restrict__ g,
                                            const float* __restrict__ b,
                                            unsigned short* __restrict__ y) {
  int row = blockIdx.x, tid = threadIdx.x;
  float4 v = reinterpret_cast<const float4*>(x + (size_t)row * 1024)[tid];
  float s  = v.x + v.y + v.z + v.w;
  float s2 = v.x * v.x + v.y * v.y + v.z * v.z + v.w * v.w;
#pragma unroll
  for (int m = 1; m < 64; m <<= 1) { s += __shfl_xor(s, m); s2 += __shfl_xor(s2, m); }
  __shared__ float ps[8];
  int w = tid >> 6;
  if ((tid & 63) == 0) { ps[w] = s; ps[4 + w] = s2; }
  __syncthreads();
  s  = ps[0] + ps[1] + ps[2] + ps[3];
  s2 = ps[4] + ps[5] + ps[6] + ps[7];
  float mu   = s * (1.0f / 1024.0f);
  float var  = fmaxf(s2 * (1.0f / 1024.0f) - mu * mu, 0.f);
  float rstd = rsqrtf(var + 1e-5f);
  float4 gv = reinterpret_cast<const float4*>(g)[tid];
  float4 bv = reinterpret_cast<const float4*>(b)[tid];
  ushort4 o;
  o.x = f2b((v.x - mu) * rstd * gv.x + bv.x);
  o.y = f2b((v.y - mu) * rstd * gv.y + bv.y);
  o.z = f2b((v.z - mu) * rstd * gv.z + bv.z);
  o.w = f2b((v.w - mu) * rstd * gv.w + bv.w);
  reinterpret_cast<ushort4*>(y + (size_t)row * 1024)[tid] = o;
}

enum { EPI_QKV = 0, EPI_RESID = 1, EPI_GELU = 2 };

// ---- GEMM 256x256: 8 waves, BK=64, dbuf LDS, counted vmcnt, T2 swizzle, T5 ----
template <int EPI>
__global__ __launch_bounds__(512, 2) void k_gemm256(
    const unsigned short* __restrict__ A, const unsigned short* __restrict__ BT,
    const float* __restrict__ bias, int M, int N, int K,
    unsigned short* __restrict__ outb,
    unsigned short* __restrict__ qb, unsigned short* __restrict__ kb,
    unsigned short* __restrict__ vb) {
  __shared__ __align__(16) unsigned short Abuf[2][256][64];
  __shared__ __align__(16) unsigned short Bbuf[2][256][64];
  int nx = gridDim.x, nwg = nx * gridDim.y;
  int w0 = blockIdx.y * nx + blockIdx.x;
  int id = (w0 & 7) * (nwg >> 3) + (w0 >> 3);
  int bx = id % nx, by = id / nx;
  int m0 = by * 256, n0 = bx * 256;
  int tid = threadIdx.x;
  int lane = tid & 63, wid = tid >> 6;
  int wm = wid >> 2, wn = wid & 3;
  int l15 = lane & 15, g = lane >> 4;
  int swl = l15 & 7;
  int lrow = lane >> 3;
  int lchunk = (lane & 7) ^ lrow;
  const unsigned short* Asrc = A  + (size_t)(m0 + wid * 32 + lrow) * K + lchunk * 8;
  const unsigned short* Bsrc = BT + (size_t)(n0 + wid * 32 + lrow) * K + lchunk * 8;
  auto stage = [&](int buf, int k0) {
#pragma unroll
    for (int i = 0; i < 4; ++i)
      gl16(Asrc + k0 + (size_t)i * 8 * K, &Abuf[buf][wid * 32 + i * 8][0]);
#pragma unroll
    for (int i = 0; i < 4; ++i)
      gl16(Bsrc + k0 + (size_t)i * 8 * K, &Bbuf[buf][wid * 32 + i * 8][0]);
  };
  f32x4 acc[8][4] = {};
  int nt = K >> 6;
  stage(0, 0);
  stage(1, 64);
  asm volatile("s_waitcnt vmcnt(8)" ::: "memory");
  __builtin_amdgcn_sched_barrier(0);
  __builtin_amdgcn_s_barrier();
  int cur = 0;
  for (int t = 0; t < nt; ++t) {
    const unsigned short (*As)[64] = Abuf[cur];
    const unsigned short (*Bs)[64] = Bbuf[cur];
    short8 a0[8], b0[4], a1[8], b1[4];
#pragma unroll
    for (int mi = 0; mi < 8; ++mi)
      a0[mi] = *reinterpret_cast<const short8*>(&As[wm * 128 + mi * 16 + l15][(g ^ swl) * 8]);
#pragma unroll
    for (int ni = 0; ni < 4; ++ni)
      b0[ni] = *reinterpret_cast<const short8*>(&Bs[wn * 64 + ni * 16 + l15][(g ^ swl) * 8]);
    __builtin_amdgcn_s_setprio(1);
#pragma unroll
    for (int mi = 0; mi < 8; ++mi)
#pragma unroll
      for (int ni = 0; ni < 4; ++ni)
        acc[mi][ni] = __builtin_amdgcn_mfma_f32_16x16x32_bf16(a0[mi], b0[ni], acc[mi][ni], 0, 0, 0);
    __builtin_amdgcn_s_setprio(0);
#pragma unroll
    for (int mi = 0; mi < 8; ++mi)
      a1[mi] = *reinterpret_cast<const short8*>(&As[wm * 128 + mi * 16 + l15][((4 + g) ^ swl) * 8]);
#pragma unroll
    for (int ni = 0; ni < 4; ++ni)
      b1[ni] = *reinterpret_cast<const short8*>(&Bs[wn * 64 + ni * 16 + l15][((4 + g) ^ swl) * 8]);
    asm volatile("s_waitcnt lgkmcnt(0)" ::: "memory");
    __builtin_amdgcn_sched_barrier(0);
    __builtin_amdgcn_s_barrier();
    __builtin_amdgcn_sched_barrier(0);
    if (t + 2 < nt) stage(cur, (t + 2) << 6);
    __builtin_amdgcn_s_setprio(1);
#pragma unroll
    for (int mi = 0; mi < 8; ++mi)
#pragma unroll
      for (int ni = 0; ni < 4; ++ni)
        acc[mi][ni] = __builtin_amdgcn_mfma_f32_16x16x32_bf16(a1[mi], b1[ni], acc[mi][ni], 0, 0, 0);
    __builtin_amdgcn_s_setprio(0);
    if (t + 2 < nt) {
      asm volatile("s_waitcnt vmcnt(8)" ::: "memory");
    } else if (t + 1 < nt) {
      asm volatile("s_waitcnt vmcnt(0)" ::: "memory");
    }
    __builtin_amdgcn_sched_barrier(0);
    __builtin_amdgcn_s_barrier();
    cur ^= 1;
  }
#pragma unroll
  for (int mi = 0; mi < 8; ++mi) {
#pragma unroll
    for (int ni = 0; ni < 4; ++ni) {
      int row0 = m0 + wm * 128 + mi * 16 + g * 4;
      int col  = n0 + wn * 64 + ni * 16 + l15;
      float bcol = bias[col];
#pragma unroll
      for (int j = 0; j < 4; ++j) {
        int r = row0 + j;
        float vv = acc[mi][ni][j] + bcol;
        if (EPI == EPI_QKV) {
          int which = col >> 10;
          int hc = col & 1023;
          int h = hc >> 6, d = hc & 63;
          int bb = r >> 11, ss = r & 2047;
          size_t idx = (((size_t)(bb * 16 + h)) * 2048 + ss) * 64 + d;
          unsigned short bv_ = f2b(which == 0 ? vv * 0.18033688011112042f : vv);
          if (which == 0)      qb[idx] = bv_;
          else if (which == 1) kb[idx] = bv_;
          else                 vb[idx] = bv_;
        } else {
          float ge = 0.5f * vv * (1.0f + erff(vv * 0.70710678118654752f));
          outb[(size_t)r * N + col] = f2b(ge);
        }
      }
    }
  }
}

// ---- GEMM 128x128, 8 waves (64x32/wave), BK=64, dbuf, counted vmcnt ----
// For N=1024 outputs (grid must reach 256 blocks): AO and Proj, fp32+resid out.
__global__ __launch_bounds__(512) void k_gemm512(
    const unsigned short* __restrict__ A, const unsigned short* __restrict__ BT,
    const float* __restrict__ bias, int M, int N, int K,
    float* __restrict__ outf, const float* __restrict__ resid) {
  __shared__ __align__(16) unsigned short Abuf[2][128][64];
  __shared__ __align__(16) unsigned short Bbuf[2][128][64];
  int nx = gridDim.x, nwg = nx * gridDim.y;
  int w0 = blockIdx.y * nx + blockIdx.x;
  int id = (w0 & 7) * (nwg >> 3) + (w0 >> 3);
  int bx = id % nx, by = id / nx;
  int m0 = by * 128, n0 = bx * 128;
  int tid = threadIdx.x;
  int lane = tid & 63, wid = tid >> 6;
  int wm = wid >> 2, wn = wid & 3;          // 2M x 4N waves; wave tile 64x32
  int l15 = lane & 15, g = lane >> 4;
  int swl = l15 & 7;
  int lrow = lane >> 3;
  int lchunk = (lane & 7) ^ lrow;
  const unsigned short* Asrc = A  + (size_t)(m0 + wid * 16 + lrow) * K + lchunk * 8;
  const unsigned short* Bsrc = BT + (size_t)(n0 + wid * 16 + lrow) * K + lchunk * 8;
  auto stage = [&](int buf, int k0) {
#pragma unroll
    for (int i = 0; i < 2; ++i)
      gl16(Asrc + k0 + (size_t)i * 8 * K, &Abuf[buf][wid * 16 + i * 8][0]);
#pragma unroll
    for (int i = 0; i < 2; ++i)
      gl16(Bsrc + k0 + (size_t)i * 8 * K, &Bbuf[buf][wid * 16 + i * 8][0]);
  };
  f32x4 acc[4][2] = {};
  int nt = K >> 6;
  stage(0, 0);
  stage(1, 64);
  asm volatile("s_waitcnt vmcnt(4)" ::: "memory");
  __builtin_amdgcn_sched_barrier(0);
  __builtin_amdgcn_s_barrier();
  int cur = 0;
  for (int t = 0; t < nt; ++t) {
    const unsigned short (*As)[64] = Abuf[cur];
    const unsigned short (*Bs)[64] = Bbuf[cur];
    short8 a0[4], b0[2], a1[4], b1[2];
#pragma unroll
    for (int mi = 0; mi < 4; ++mi)
      a0[mi] = *reinterpret_cast<const short8*>(&As[wm * 64 + mi * 16 + l15][(g ^ swl) * 8]);
#pragma unroll
    for (int ni = 0; ni < 2; ++ni)
      b0[ni] = *reinterpret_cast<const short8*>(&Bs[wn * 32 + ni * 16 + l15][(g ^ swl) * 8]);
    __builtin_amdgcn_s_setprio(1);
#pragma unroll
    for (int mi = 0; mi < 4; ++mi)
#pragma unroll
      for (int ni = 0; ni < 2; ++ni)
        acc[mi][ni] = __builtin_amdgcn_mfma_f32_16x16x32_bf16(a0[mi], b0[ni], acc[mi][ni], 0, 0, 0);
    __builtin_amdgcn_s_setprio(0);
#pragma unroll
    for (int mi = 0; mi < 4; ++mi)
      a1[mi] = *reinterpret_cast<const short8*>(&As[wm * 64 + mi * 16 + l15][((4 + g) ^ swl) * 8]);
#pragma unroll
    for (int ni = 0; ni < 2; ++ni)
      b1[ni] = *reinterpret_cast<const short8*>(&Bs[wn * 32 + ni * 16 + l15][((4 + g) ^ swl) * 8]);
    asm volatile("s_waitcnt lgkmcnt(0)" ::: "memory");
    __builtin_amdgcn_sched_barrier(0);
    __builtin_amdgcn_s_barrier();
    __builtin_amdgcn_sched_barrier(0);
    if (t + 2 < nt) stage(cur, (t + 2) << 6);
    __builtin_amdgcn_s_setprio(1);
#pragma unroll
    for (int mi = 0; mi < 4; ++mi)
#pragma unroll
      for (int ni = 0; ni < 2; ++ni)
        acc[mi][ni] = __builtin_amdgcn_mfma_f32_16x16x32_bf16(a1[mi], b1[ni], acc[mi][ni], 0, 0, 0);
    __builtin_amdgcn_s_setprio(0);
    if (t + 2 < nt) {
      asm volatile("s_waitcnt vmcnt(4)" ::: "memory");
    } else if (t + 1 < nt) {
      asm volatile("s_waitcnt vmcnt(0)" ::: "memory");
    }
    __builtin_amdgcn_sched_barrier(0);
    __builtin_amdgcn_s_barrier();
    cur ^= 1;
  }
#pragma unroll
  for (int mi = 0; mi < 4; ++mi) {
#pragma unroll
    for (int ni = 0; ni < 2; ++ni) {
      int row0 = m0 + wm * 64 + mi * 16 + g * 4;
      int col  = n0 + wn * 32 + ni * 16 + l15;
      float bcol = bias[col];
#pragma unroll
      for (int j = 0; j < 4; ++j) {
        size_t idx = (size_t)(row0 + j) * N + col;
        outf[idx] = acc[mi][ni][j] + bcol + resid[idx];
      }
    }
  }
}

// ---- flash attention: grid (32, 32), 4 waves x 16 q-rows, KVBLK=64 ----
__global__ __launch_bounds__(256) void k_attn(
    const unsigned short* __restrict__ qb, const unsigned short* __restrict__ kb,
    const unsigned short* __restrict__ vt, unsigned short* __restrict__ attn_out) {
  __shared__ __align__(16) unsigned short Ks[64][64];
  __shared__ __align__(16) unsigned short Vs[64][64];
  __shared__ __align__(16) unsigned short Plds[4][16][72];
  int bh = blockIdx.y;
  int b = bh >> 4, h = bh & 15;
  int tid = threadIdx.x;
  int lane = tid & 63, wid = tid >> 6;
  int l15 = lane & 15, g = lane >> 4;
  int q0 = blockIdx.x * 64 + wid * 16;
  const unsigned short* Qb = qb + (size_t)bh * 2048 * 64;
  const unsigned short* Kb = kb + (size_t)bh * 2048 * 64;
  const unsigned short* Vt = vt + (size_t)bh * 64 * 2048;
  short8 qf0 = *reinterpret_cast<const short8*>(&Qb[(size_t)(q0 + l15) * 64 + g * 8]);
  short8 qf1 = *reinterpret_cast<const short8*>(&Qb[(size_t)(q0 + l15) * 64 + 32 + g * 8]);
  float mj = -1e30f, lj = 0.f;
  f32x4 o[4] = {};
  int sr  = wid * 16 + (lane >> 3);
  int scn = (lane & 7) ^ (sr & 7);
  int swl = l15 & 7;
  for (int t0 = 0; t0 < 2048; t0 += 64) {
    __syncthreads();
    gl16(Kb + (size_t)(t0 + sr) * 64 + scn * 8,       &Ks[wid * 16][0]);
    gl16(Kb + (size_t)(t0 + sr + 8) * 64 + scn * 8,   &Ks[wid * 16 + 8][0]);
    gl16(Vt + (size_t)sr * 2048 + t0 + scn * 8,       &Vs[wid * 16][0]);
    gl16(Vt + (size_t)(sr + 8) * 2048 + t0 + scn * 8, &Vs[wid * 16 + 8][0]);
    __syncthreads();
    f32x4 scv[4];
#pragma unroll
    for (int kk = 0; kk < 4; ++kk) {
      short8 kf0 = *reinterpret_cast<const short8*>(&Ks[kk * 16 + l15][(g ^ swl) * 8]);
      short8 kf1 = *reinterpret_cast<const short8*>(&Ks[kk * 16 + l15][((4 + g) ^ swl) * 8]);
      f32x4 z = {};
      z = __builtin_amdgcn_mfma_f32_16x16x32_bf16(kf0, qf0, z, 0, 0, 0);
      scv[kk] = __builtin_amdgcn_mfma_f32_16x16x32_bf16(kf1, qf1, z, 0, 0, 0);
    }
    float mx = -1e30f;
#pragma unroll
    for (int kk = 0; kk < 4; ++kk)
#pragma unroll
      for (int j = 0; j < 4; ++j) mx = fmaxf(mx, scv[kk][j]);
    mx = fmaxf(mx, __shfl_xor(mx, 16));
    mx = fmaxf(mx, __shfl_xor(mx, 32));
    bool skip = __all(mx <= mj + 8.0f);
    float mnew = skip ? mj : fmaxf(mj, mx);
    float p[16];
    float ts = 0.f;
#pragma unroll
    for (int kk = 0; kk < 4; ++kk)
#pragma unroll
      for (int j = 0; j < 4; ++j) {
        float pv = __builtin_amdgcn_exp2f(scv[kk][j] - mnew);
        p[kk * 4 + j] = pv;
        ts += pv;
      }
    ts += __shfl_xor(ts, 16);
    ts += __shfl_xor(ts, 32);
    if (!skip) {
      float ef = __builtin_amdgcn_exp2f(mj - mnew);
      int sb = 20 * g;
      float e0 = __shfl(ef, sb + 0), e1 = __shfl(ef, sb + 1);
      float e2 = __shfl(ef, sb + 2), e3 = __shfl(ef, sb + 3);
#pragma unroll
      for (int ct = 0; ct < 4; ++ct) {
        o[ct][0] *= e0; o[ct][1] *= e1; o[ct][2] *= e2; o[ct][3] *= e3;
      }
      lj = lj * ef + ts;
      mj = mnew;
    } else {
      lj += ts;
    }
#pragma unroll
    for (int kk = 0; kk < 4; ++kk) {
      unsigned r0, r1;
      asm("v_cvt_pk_bf16_f32 %0, %1, %2" : "=v"(r0) : "v"(p[kk * 4 + 0]), "v"(p[kk * 4 + 1]));
      asm("v_cvt_pk_bf16_f32 %0, %1, %2" : "=v"(r1) : "v"(p[kk * 4 + 2]), "v"(p[kk * 4 + 3]));
      unsigned long long w = (unsigned long long)r0 | ((unsigned long long)r1 << 32);
      *reinterpret_cast<unsigned long long*>(&Plds[wid][l15][kk * 16 + g * 4]) = w;
    }
    short8 pf0 = *reinterpret_cast<const short8*>(&Plds[wid][l15][g * 8]);
    short8 pf1 = *reinterpret_cast<const short8*>(&Plds[wid][l15][32 + g * 8]);
#pragma unroll
    for (int ct = 0; ct < 4; ++ct) {
      short8 vf0 = *reinterpret_cast<const short8*>(&Vs[ct * 16 + l15][(g ^ swl) * 8]);
      short8 vf1 = *reinterpret_cast<const short8*>(&Vs[ct * 16 + l15][((4 + g) ^ swl) * 8]);
      o[ct] = __builtin_amdgcn_mfma_f32_16x16x32_bf16(pf0, vf0, o[ct], 0, 0, 0);
      o[ct] = __builtin_amdgcn_mfma_f32_16x16x32_bf16(pf1, vf1, o[ct], 0, 0, 0);
    }
  }
  float invq = 1.0f / lj;
  int sb = 20 * g;
  float i0 = __shfl(invq, sb + 0), i1 = __shfl(invq, sb + 1);
  float i2 = __shfl(invq, sb + 2), i3 = __shfl(invq, sb + 3);
  float iv[4] = {i0, i1, i2, i3};
#pragma unroll
  for (int j = 0; j < 4; ++j) {
    size_t t = (size_t)b * 2048 + (q0 + g * 4 + j);
#pragma unroll
    for (int ct = 0; ct < 4; ++ct)
      attn_out[t * 1024 + h * 64 + ct * 16 + l15] = f2b(o[ct][j] * iv[j]);
  }
}

extern "C" void kernel_launch(void* const* d_in, const int* in_sizes, int n_in,
                              void* d_out, int out_size, void* d_ws, size_t ws_size,
                              hipStream_t stream) {
  (void)in_sizes; (void)n_in; (void)out_size; (void)ws_size;
  const float* x      = (const float*)d_in[0];
  const float* ln1_g  = (const float*)d_in[1];
  const float* ln1_b  = (const float*)d_in[2];
  const float* w_qkv  = (const float*)d_in[3];
  const float* b_qkv  = (const float*)d_in[4];
  const float* w_ao   = (const float*)d_in[5];
  const float* b_ao   = (const float*)d_in[6];
  const float* ln2_g  = (const float*)d_in[7];
  const float* ln2_b  = (const float*)d_in[8];
  const float* w_fc   = (const float*)d_in[9];
  const float* b_fc   = (const float*)d_in[10];
  const float* w_proj = (const float*)d_in[11];
  const float* b_proj = (const float*)d_in[12];
  float* out = (float*)d_out;

  char* ws = (char*)d_ws;
  size_t o = 0;
  auto nxt = [&](size_t bytes) { void* p = ws + o; o += (bytes + 255) & ~(size_t)255; return p; };
  unsigned short* wT_qkv  = (unsigned short*)nxt((size_t)3072 * 1024 * 2);
  unsigned short* wT_ao   = (unsigned short*)nxt((size_t)1024 * 1024 * 2);
  unsigned short* wT_fc   = (unsigned short*)nxt((size_t)4096 * 1024 * 2);
  unsigned short* wT_proj = (unsigned short*)nxt((size_t)1024 * 4096 * 2);
  unsigned short* h_ln    = (unsigned short*)nxt((size_t)4096 * 1024 * 2);
  unsigned short* qbuf    = (unsigned short*)nxt((size_t)4096 * 1024 * 2);
  unsigned short* kbuf    = (unsigned short*)nxt((size_t)4096 * 1024 * 2);
  unsigned short* vbuf    = (unsigned short*)nxt((size_t)4096 * 1024 * 2);
  unsigned short* vtb     = (unsigned short*)nxt((size_t)4096 * 1024 * 2);
  float*          out1    = (float*)nxt((size_t)4096 * 1024 * 4);
  unsigned short* fc_buf  = qbuf;
  unsigned short* attn_o  = vbuf;

  dim3 b32(32, 8, 1);
  k_tcvt<<<dim3(96, 32), b32, 0, stream>>>(w_qkv, wT_qkv, 1024, 3072);
  k_tcvt<<<dim3(32, 32), b32, 0, stream>>>(w_ao, wT_ao, 1024, 1024);
  k_tcvt<<<dim3(128, 32), b32, 0, stream>>>(w_fc, wT_fc, 1024, 4096);
  k_tcvt<<<dim3(32, 128), b32, 0, stream>>>(w_proj, wT_proj, 4096, 1024);

  k_ln<<<4096, 256, 0, stream>>>(x, ln1_g, ln1_b, h_ln);
  k_gemm256<EPI_QKV><<<dim3(12, 16), 512, 0, stream>>>(h_ln, wT_qkv, b_qkv, 4096, 3072, 1024,
                                                       nullptr, qbuf, kbuf, vbuf);
  k_tv<<<dim3(2, 64, 32), b32, 0, stream>>>(vbuf, vtb);
  k_attn<<<dim3(32, 32), 256, 0, stream>>>(qbuf, kbuf, vtb, attn_o);
  k_gemm512<<<dim3(8, 32), 512, 0, stream>>>(attn_o, wT_ao, b_ao, 4096, 1024, 1024,
                                             out1, x);
  k_ln<<<4096, 256, 0, stream>>>(out1, ln2_g, ln2_b, h_ln);
  k_gemm256<EPI_GELU><<<dim3(16, 16), 512, 0, stream>>>(h_ln, wT_fc, b_fc, 4096, 4096, 1024,
                                                        fc_buf, nullptr, nullptr, nullptr);
  k_gemm512<<<dim3(8, 32), 512, 0, stream>>>(fc_buf, wT_proj, b_proj, 4096, 1024, 4096,
                                             out, out1);
}